// Round 11
// baseline (325.175 us; speedup 1.0000x reference)
//
#include <hip/hip_runtime.h>

// Round 11: (1) p4 eliminated — p3 scatters raw extremes into BEV via
// order-preserving uint-key atomicMax (min-channels negated); k_binit fills
// key(-inf); conv layer 0 decodes + applies BN3 in staging (monotone-affine
// commutes with max). (2) PGRID 2048 (TLP was the missing resource, not
// pipeline depth). Convs otherwise unchanged.

#define BATCH 2
#define NPTS 100000
#define GNX 176
#define GNY 200
#define GNZ 10
#define NCELL (GNX*GNY*GNZ)
#define PMAX 32
#define MAXV 20000
#define NVOX (BATCH*MAXV)
#define NPFN (NVOX*PMAX)
#define CONVH 200
#define CONVW 176
#define NPIX (CONVH*CONVW)
#define NELEM (BATCH*NPIX*64)
#define SCAN_NB ((NCELL + 1023)/1024)
#define PGRID 2048
#define SHAD 32
#define KNEGINF 0x007FFFFFu   // key(-inf): u=0xFF800000, key=~u

typedef __attribute__((ext_vector_type(8))) short short8;
typedef __attribute__((ext_vector_type(4))) float f32x4;

__device__ __forceinline__ unsigned short f2bf(float f){
  unsigned int u = __float_as_uint(f);
  u = (u + 0x7fffu + ((u >> 16) & 1u)) >> 16;
  return (unsigned short)u;
}

__device__ __forceinline__ int voxel_id(float x, float y, float z){
  int ix = (int)floorf(x / 0.4f);
  int iy = (int)floorf((y + 40.0f) / 0.4f);
  int iz = (int)floorf((z + 3.0f) / 0.4f);
  if (ix < 0 || iy < 0 || iz < 0 || ix >= GNX || iy >= GNY || iz >= GNZ) return -1;
  return (ix*GNY + iy)*GNZ + iz;
}

extern "C" __global__ void k_count(const float* __restrict__ pts, int* __restrict__ cellcnt){
  int i = blockIdx.x*256 + threadIdx.x;
  if (i >= BATCH*NPTS) return;
  const float* q = pts + (size_t)i*4;
  int vid = voxel_id(q[0], q[1], q[2]);
  if (vid < 0) return;
  int b = i / NPTS;
  atomicAdd(&cellcnt[b*NCELL + vid], 1);
}

extern "C" __global__ void __launch_bounds__(256) k_blkcount(const int* __restrict__ cellcnt,
                                                             int* __restrict__ blks){
  int b = blockIdx.y, blk = blockIdx.x, t = threadIdx.x;
  int base = blk*1024 + t*4;
  int s = 0;
  #pragma unroll
  for (int i=0;i<4;i++){ int c = base+i; if (c < NCELL) s += (cellcnt[b*NCELL+c] > 0); }
  #pragma unroll
  for (int m=32;m>=1;m>>=1) s += __shfl_xor(s, m);
  __shared__ int red[4];
  if ((t&63)==0) red[t>>6] = s;
  __syncthreads();
  if (t==0) blks[b*512+blk] = red[0]+red[1]+red[2]+red[3];
}

extern "C" __global__ void __launch_bounds__(512) k_scan(int* __restrict__ blks){
  int b = blockIdx.x, t = threadIdx.x;
  __shared__ int l[512];
  int orig = (t < SCAN_NB) ? blks[b*512+t] : 0;
  l[t] = orig;
  __syncthreads();
  for (int o=1;o<512;o<<=1){
    int v = (t>=o) ? l[t-o] : 0;
    __syncthreads();
    l[t] += v;
    __syncthreads();
  }
  if (t < SCAN_NB) blks[b*512+t] = l[t] - orig;   // exclusive
}

extern "C" __global__ void __launch_bounds__(256) k_assign(const int* __restrict__ cellcnt,
    const int* __restrict__ blks, int* __restrict__ slotmap, int* __restrict__ vv,
    int* __restrict__ cnt){
  int b = blockIdx.y, blk = blockIdx.x, t = threadIdx.x;
  int base = blk*1024 + t*4;
  int flag[4]; int s = 0;
  #pragma unroll
  for (int i=0;i<4;i++){
    int c = base+i;
    flag[i] = (c < NCELL) ? (cellcnt[b*NCELL+c] > 0) : 0;
    s += flag[i];
  }
  __shared__ int lds[256];
  lds[t] = s; __syncthreads();
  for (int o=1;o<256;o<<=1){
    int v = (t>=o) ? lds[t-o] : 0;
    __syncthreads();
    lds[t] += v;
    __syncthreads();
  }
  int run = blks[b*512+blk] + (lds[t]-s);
  #pragma unroll
  for (int i=0;i<4;i++){
    int c = base+i;
    if (c >= NCELL) break;
    int sm = -1;
    if (flag[i]){
      if (run < MAXV){
        sm = run;
        vv[b*MAXV+run]  = c;
        cnt[b*MAXV+run] = min(cellcnt[b*NCELL+c], PMAX);
      }
      run++;
    }
    slotmap[b*NCELL+c] = sm;
  }
}

extern "C" __global__ void k_fill(const float* __restrict__ pts, const int* __restrict__ slotmap,
                                  int* __restrict__ fill, int* __restrict__ plist){
  int i = blockIdx.x*256 + threadIdx.x;
  if (i >= BATCH*NPTS) return;
  const float* q = pts + (size_t)i*4;
  int vid = voxel_id(q[0], q[1], q[2]);
  if (vid < 0) return;
  int b = i / NPTS;
  int slot = slotmap[b*NCELL+vid];
  if (slot < 0) return;
  int pos = atomicAdd(&fill[b*MAXV+slot], 1);
  if (pos < PMAX) plist[((size_t)b*MAXV+slot)*PMAX + pos] = i - b*NPTS;
}

// gather sorted points into pvox [NVOX][32] float4 + per-voxel mean [NVOX] float4
extern "C" __global__ void __launch_bounds__(256) k_feat(const float* __restrict__ pts,
    const int* __restrict__ cnt, const int* __restrict__ plist,
    float* __restrict__ pvox, float* __restrict__ mean){
  int g  = threadIdx.x >> 5;
  int fv = blockIdx.x*8 + g;
  int p  = threadIdx.x & 31;
  int b  = fv / MAXV;
  __shared__ int lst[8][32];
  int c = cnt[fv];
  if (p < c) lst[g][p] = plist[(size_t)fv*PMAX + p];
  __syncthreads();
  if (p == 0){
    for (int i=1;i<c;i++){
      int key = lst[g][i]; int j = i-1;
      while (j >= 0 && lst[g][j] > key){ lst[g][j+1] = lst[g][j]; j--; }
      lst[g][j+1] = key;
    }
  }
  __syncthreads();
  float4 pt = make_float4(0.f,0.f,0.f,0.f);
  if (p < c) pt = *(const float4*)(pts + ((size_t)b*NPTS + lst[g][p])*4);
  float sx = pt.x, sy = pt.y, sz = pt.z;
  #pragma unroll
  for (int m=16;m>=1;m>>=1){
    sx += __shfl_xor(sx, m, 32); sy += __shfl_xor(sy, m, 32); sz += __shfl_xor(sz, m, 32);
  }
  float cd = (float)max(c, 1);
  if (p < c) *(float4*)(pvox + ((size_t)fv*32 + p)*4) = pt;
  if (p == 0) *(float4*)(mean + (size_t)fv*4) = make_float4(sx/cd, sy/cd, sz/cd, 0.f);
}

// BEV key init: every element = key(-inf)
extern "C" __global__ void k_binit(unsigned* __restrict__ bev){
  int i = blockIdx.x*256 + threadIdx.x;
  if (i*4 >= NELEM) return;
  uint4 v = make_uint4(KNEGINF, KNEGINF, KNEGINF, KNEGINF);
  ((uint4*)bev)[i] = v;
}

#define IN7(pt, mn) {pt.x, pt.y, pt.z, pt.w, pt.x-mn.x, pt.y-mn.y, pt.z-mn.z}

// ============ PFN phases: software-pipelined voxel loops ============
extern "C" __global__ void __launch_bounds__(256) k_p1(const float* __restrict__ pvox,
    const float* __restrict__ mean, const int* __restrict__ cnt,
    const float* __restrict__ w1, float* __restrict__ st){
  __shared__ float w1L[224];
  __shared__ float sred[64];
  int tid = threadIdx.x;
  if (tid < 56) ((float4*)w1L)[tid] = ((const float4*)w1)[tid];
  if (tid < 64) sred[tid] = 0.f;
  __syncthreads();
  int w = tid>>6, lane = tid&63, c = lane&31, half = lane>>5;
  const int STR = PGRID*4;
  int fv = blockIdx.x*4 + w;
  int c_n = 0;
  float4 mn_n = make_float4(0.f,0.f,0.f,0.f), pA_n = mn_n;
  if (fv < NVOX){
    c_n  = cnt[fv];
    mn_n = *(const float4*)(mean + (size_t)fv*4);
    pA_n = *(const float4*)(pvox + ((size_t)fv*32 + half)*4);
  }
  float S=0.f, Q=0.f;
  while (fv < NVOX){
    const int fvc = fv;
    const int c_ = c_n;
    const float4 mn = mn_n, pA = pA_n;
    fv += STR;
    if (fv < NVOX){
      c_n  = cnt[fv];
      mn_n = *(const float4*)(mean + (size_t)fv*4);
      pA_n = *(const float4*)(pvox + ((size_t)fv*32 + half)*4);
    }
    {
      float in[7] = IN7(pA, mn);
      float v = 0.f;
      #pragma unroll
      for (int k=0;k<7;k++) v += in[k]*w1L[k*32+c];
      if (half < c_){ S += v; Q += v*v; }
    }
    for (int p = half+2; p < c_; p += 2){
      float4 pt = *(const float4*)(pvox + ((size_t)fvc*32+p)*4);
      float in[7] = IN7(pt, mn);
      float v = 0.f;
      #pragma unroll
      for (int k=0;k<7;k++) v += in[k]*w1L[k*32+c];
      S += v; Q += v*v;
    }
  }
  S += __shfl_xor(S,32); Q += __shfl_xor(Q,32);
  if (half==0){ atomicAdd(&sred[c],S); atomicAdd(&sred[32+c],Q); }
  __syncthreads();
  if (tid<64) atomicAdd(&st[(blockIdx.x&(SHAD-1))*64+tid], sred[tid]);
}

extern "C" __global__ void __launch_bounds__(256) k_p2(const float* __restrict__ pvox,
    const float* __restrict__ mean, const int* __restrict__ cnt,
    const float* __restrict__ w1, const float* __restrict__ g1, const float* __restrict__ b1,
    const float* __restrict__ w2, const float* __restrict__ st1, float* __restrict__ st2,
    float* __restrict__ K2buf){
  __shared__ float w1L[224];
  __shared__ float w2L[2496];
  __shared__ float sred[128];
  int tid = threadIdx.x;
  if (tid < 56) ((float4*)w1L)[tid] = ((const float4*)w1)[tid];
  for (int i=tid;i<624;i+=256) ((float4*)w2L)[i] = ((const float4*)w2)[i];
  if (tid < 128) sred[tid] = 0.f;
  __syncthreads();
  int w = tid>>6, lane = tid&63, c1 = lane&31;
  const float invN = 1.f/(float)NPFN;
  float m1=0.f, v1s=0.f;
  #pragma unroll
  for (int s=0;s<SHAD;s++){ m1 += st1[s*64+c1]; v1s += st1[s*64+32+c1]; }
  m1 *= invN; v1s = v1s*invN - m1*m1;
  float sc1 = g1[c1]*rsqrtf(v1s + 1e-3f);
  float sh1 = b1[c1] - m1*sc1;
  const int STR = PGRID*4;
  int fv = blockIdx.x*4 + w;
  int c_n = 0;
  float4 mn_n = make_float4(0.f,0.f,0.f,0.f), p0_n = mn_n, p1_n = mn_n;
  if (fv < NVOX){
    c_n  = cnt[fv];
    mn_n = *(const float4*)(mean + (size_t)fv*4);
    p0_n = *(const float4*)(pvox + ((size_t)fv*32+0)*4);
    p1_n = *(const float4*)(pvox + ((size_t)fv*32+1)*4);
  }
  float S = 0.f, Q = 0.f;
  while (fv < NVOX){
    const int fvc = fv;
    const int c_ = c_n;
    const float4 mn = mn_n, p0 = p0_n, p1 = p1_n;
    fv += STR;
    if (fv < NVOX){
      c_n  = cnt[fv];
      mn_n = *(const float4*)(mean + (size_t)fv*4);
      p0_n = *(const float4*)(pvox + ((size_t)fv*32+0)*4);
      p1_n = *(const float4*)(pvox + ((size_t)fv*32+1)*4);
    }
    float vm = 0.f, sa = 0.f, sq = 0.f;
    {
      float in[7] = IN7(p0, mn);
      float v1 = 0.f, a2 = 0.f;
      #pragma unroll
      for (int k=0;k<7;k++){ v1 += in[k]*w1L[k*32+c1]; a2 += in[k]*w2L[k*64+lane]; }
      if (c_ > 0){ vm = fmaxf(vm, v1*sc1 + sh1); sa += a2; sq += a2*a2; }
    }
    {
      float in[7] = IN7(p1, mn);
      float v1 = 0.f, a2 = 0.f;
      #pragma unroll
      for (int k=0;k<7;k++){ v1 += in[k]*w1L[k*32+c1]; a2 += in[k]*w2L[k*64+lane]; }
      if (c_ > 1){ vm = fmaxf(vm, v1*sc1 + sh1); sa += a2; sq += a2*a2; }
    }
    for (int p = 2; p < c_; p++){
      float4 pt = *(const float4*)(pvox + ((size_t)fvc*32+p)*4);
      float in[7] = IN7(pt, mn);
      float v1 = 0.f, a2 = 0.f;
      #pragma unroll
      for (int k=0;k<7;k++){ v1 += in[k]*w1L[k*32+c1]; a2 += in[k]*w2L[k*64+lane]; }
      vm = fmaxf(vm, v1*sc1 + sh1);
      sa += a2; sq += a2*a2;
    }
    float k0=0.f,k1=0.f,k2=0.f,k3=0.f;
    #pragma unroll
    for (int j=0;j<32;j+=4){
      k0 += __shfl(vm, j  )*w2L[(7+j )*64+lane];
      k1 += __shfl(vm, j+1)*w2L[(8+j )*64+lane];
      k2 += __shfl(vm, j+2)*w2L[(9+j )*64+lane];
      k3 += __shfl(vm, j+3)*w2L[(10+j)*64+lane];
    }
    float K = (k0+k1)+(k2+k3);
    if (c_) K2buf[(size_t)fvc*64 + lane] = K;
    S += (float)PMAX*K + sa;
    Q += (float)PMAX*K*K + sq + 2.f*K*sa;
  }
  atomicAdd(&sred[lane], S); atomicAdd(&sred[64+lane], Q);
  __syncthreads();
  if (tid < 128) atomicAdd(&st2[(blockIdx.x&(SHAD-1))*128 + tid], sred[tid]);
}

// p3: single point pass; scatters raw extreme (asel + K3) into BEV via
// order-preserving uint key atomicMax (min-channels negated).
extern "C" __global__ void __launch_bounds__(256) k_p3(const float* __restrict__ pvox,
    const float* __restrict__ mean, const int* __restrict__ cnt, const int* __restrict__ vv,
    const float* __restrict__ w2, const float* __restrict__ g2, const float* __restrict__ b2,
    const float* __restrict__ w3, const float* __restrict__ g3,
    const float* __restrict__ st2, float* __restrict__ st3,
    const float* __restrict__ K2buf, unsigned* __restrict__ bev){
  __shared__ float w2L[2496];
  __shared__ float w3L[4544];
  __shared__ float sred[128];
  int tid = threadIdx.x;
  for (int i=tid;i<624;i+=256)  ((float4*)w2L)[i] = ((const float4*)w2)[i];
  for (int i=tid;i<1136;i+=256) ((float4*)w3L)[i] = ((const float4*)w3)[i];
  if (tid < 128) sred[tid] = 0.f;
  __syncthreads();
  int w = tid>>6, lane = tid&63;
  const float invN = 1.f/(float)NPFN;
  float m2=0.f, v2s=0.f;
  #pragma unroll
  for (int s=0;s<SHAD;s++){ m2 += st2[s*128+lane]; v2s += st2[s*128+64+lane]; }
  m2 *= invN; v2s = v2s*invN - m2*m2;
  float sc2 = g2[lane]*rsqrtf(v2s + 1e-3f);
  float sh2 = b2[lane] - m2*sc2;
  bool pickmax = (g3[lane] >= 0.f);
  const int STR = PGRID*4;
  int fv = blockIdx.x*4 + w;
  int c_n = 0, vv_n = 0; float K2_n = 0.f;
  float4 mn_n = make_float4(0.f,0.f,0.f,0.f), p0_n = mn_n, p1_n = mn_n;
  if (fv < NVOX){
    c_n  = cnt[fv];
    vv_n = vv[fv];
    mn_n = *(const float4*)(mean + (size_t)fv*4);
    K2_n = K2buf[(size_t)fv*64 + lane];
    p0_n = *(const float4*)(pvox + ((size_t)fv*32+0)*4);
    p1_n = *(const float4*)(pvox + ((size_t)fv*32+1)*4);
  }
  float S = 0.f, Q = 0.f;
  while (fv < NVOX){
    const int fvc = fv;
    const int c_ = c_n, vid = vv_n;
    const float K2 = K2_n;
    const float4 mn = mn_n, p0 = p0_n, p1 = p1_n;
    fv += STR;
    if (fv < NVOX){
      c_n  = cnt[fv];
      vv_n = vv[fv];
      mn_n = *(const float4*)(mean + (size_t)fv*4);
      K2_n = K2buf[(size_t)fv*64 + lane];
      p0_n = *(const float4*)(pvox + ((size_t)fv*32+0)*4);
      p1_n = *(const float4*)(pvox + ((size_t)fv*32+1)*4);
    }
    float vm = 0.f, sa = 0.f, sq = 0.f;
    float amx = -3.4e38f, amn = 3.4e38f;
    {
      float in[7] = IN7(p0, mn);
      float a2 = 0.f, a3 = 0.f;
      #pragma unroll
      for (int k=0;k<7;k++){ a2 += in[k]*w2L[k*64+lane]; a3 += in[k]*w3L[k*64+lane]; }
      if (c_ > 0){
        vm = fmaxf(vm, (a2+K2)*sc2 + sh2);
        sa += a3; sq += a3*a3;
        amx = fmaxf(amx, a3); amn = fminf(amn, a3);
      }
    }
    {
      float in[7] = IN7(p1, mn);
      float a2 = 0.f, a3 = 0.f;
      #pragma unroll
      for (int k=0;k<7;k++){ a2 += in[k]*w2L[k*64+lane]; a3 += in[k]*w3L[k*64+lane]; }
      if (c_ > 1){
        vm = fmaxf(vm, (a2+K2)*sc2 + sh2);
        sa += a3; sq += a3*a3;
        amx = fmaxf(amx, a3); amn = fminf(amn, a3);
      }
    }
    for (int p = 2; p < c_; p++){
      float4 pt = *(const float4*)(pvox + ((size_t)fvc*32+p)*4);
      float in[7] = IN7(pt, mn);
      float a2 = 0.f, a3 = 0.f;
      #pragma unroll
      for (int k=0;k<7;k++){ a2 += in[k]*w2L[k*64+lane]; a3 += in[k]*w3L[k*64+lane]; }
      vm = fmaxf(vm, (a2+K2)*sc2 + sh2);
      sa += a3; sq += a3*a3;
      amx = fmaxf(amx, a3); amn = fminf(amn, a3);
    }
    float k0=0.f,k1=0.f,k2=0.f,k3=0.f;
    #pragma unroll
    for (int j=0;j<64;j+=4){
      k0 += __shfl(vm, j  )*w3L[(7+j )*64+lane];
      k1 += __shfl(vm, j+1)*w3L[(8+j )*64+lane];
      k2 += __shfl(vm, j+2)*w3L[(9+j )*64+lane];
      k3 += __shfl(vm, j+3)*w3L[(10+j)*64+lane];
    }
    float K3 = (k0+k1)+(k2+k3);
    if (c_){
      float raw = (pickmax ? amx : amn) + K3;
      if (!pickmax) raw = -raw;              // min-channels: store -raw, max-reduce
      unsigned u = __float_as_uint(raw);
      unsigned key = (u & 0x80000000u) ? ~u : (u | 0x80000000u);
      int bb = fvc / MAXV;
      int cx = vid / (GNY*GNZ);
      int cy = (vid / GNZ) % GNY;
      atomicMax(bev + (((size_t)bb*NPIX + (size_t)cy*CONVW + cx)*64) + lane, key);
    }
    S += (float)PMAX*K3 + sa;
    Q += (float)PMAX*K3*K3 + sq + 2.f*K3*sa;
  }
  atomicAdd(&sred[lane], S); atomicAdd(&sred[64+lane], Q);
  __syncthreads();
  if (tid < 128) atomicAdd(&st3[(blockIdx.x&(SHAD-1))*128 + tid], sred[tid]);
}

// ---- weight prepack: [oc][ic][3][3] f32 -> [tap][oc][ic] bf16, 5 layers
extern "C" __global__ void k_wprep(const float* __restrict__ cs_w, const float* __restrict__ rpn_w,
                                   unsigned short* __restrict__ Bw){
  int i = blockIdx.x*256 + threadIdx.x;
  if (i >= 5*36864) return;
  int l = i/36864, r = i - l*36864;
  int tap = r >> 12, oc = (r >> 6) & 63, ic = r & 63;
  const float* src = (l < 2) ? (cs_w + (size_t)l*36864) : (rpn_w + (size_t)(l-2)*36864);
  Bw[i] = f2bf(src[((size_t)oc*64 + ic)*9 + tap]);
}

// ---- conv3x3: implicit GEMM, bf16 MFMA. Tile 16x*8y, fused BN/relu/cvt on
//      staging. raw0: input is uint-key BEV (decode + sign-restore).
#define CTH 8
extern "C" __global__ void __launch_bounds__(256) k_conv(const float* __restrict__ in,
    const float* __restrict__ stin, const float* __restrict__ g, const float* __restrict__ be,
    float eps, float invN, int raw0,
    const unsigned short* __restrict__ Bw, const float* __restrict__ bias,
    float* __restrict__ out, float* __restrict__ st){
  const int b  = blockIdx.z;
  const int x0 = blockIdx.x*16, y0 = blockIdx.y*CTH;
  const int tid = threadIdx.x;
  const int w = tid >> 6, l = tid & 63;
  const int l15 = l & 15, quad = l >> 4;
  const int bid = (blockIdx.z*gridDim.y + blockIdx.y)*gridDim.x + blockIdx.x;
  const int shad = bid & (SHAD-1);

  __shared__ unsigned short smemA[(CTH+2)*18*64];
  __shared__ float bnsc[64], bnsh[64];
  __shared__ float sA[64], sQ[64];
  if (tid < 64){
    sA[tid] = 0.f; sQ[tid] = 0.f;
    float m = 0.f, q = 0.f;
    #pragma unroll
    for (int s=0;s<SHAD;s++){ m += stin[s*128+tid]; q += stin[s*128+64+tid]; }
    m *= invN;
    float va = q*invN - m*m;
    float sc = g[tid]*rsqrtf(va + eps);
    bnsc[tid] = sc; bnsh[tid] = be[tid] - m*sc;
  }
  __syncthreads();

  for (int i = tid; i < (CTH+2)*18*8; i += 256){
    int pos = i >> 3, jb = i & 7;
    int yp = pos/18, xp = pos - yp*18;
    int gy = y0 + yp - 1, gx = x0 + xp - 1;
    unsigned short h[8] = {0,0,0,0,0,0,0,0};
    if (gy >= 0 && gy < CONVH && gx >= 0 && gx < CONVW){
      const float* src = in + (((size_t)b*NPIX + (size_t)gy*CONVW + gx)*64 + jb*8);
      float4 v0 = *(const float4*)src;
      float4 v1 = *(const float4*)(src+4);
      float vv[8] = {v0.x,v0.y,v0.z,v0.w,v1.x,v1.y,v1.z,v1.w};
      #pragma unroll
      for (int k=0;k<8;k++){
        int c = jb*8 + k;
        float f = vv[k];
        if (raw0){
          unsigned key = __float_as_uint(f);
          unsigned u = (key & 0x80000000u) ? (key & 0x7fffffffu) : ~key;
          f = __uint_as_float(u);
          if (bnsc[c] < 0.f) f = -f;        // min-channels were stored negated
        }
        h[k] = f2bf(fmaxf(f*bnsc[c] + bnsh[c], 0.f));
      }
    }
    int jsw = jb ^ (xp & 7);
    *(uint4*)&smemA[pos*64 + jsw*8] = *(uint4*)h;
  }
  __syncthreads();

  f32x4 acc[2][4] = {{{0.f,0.f,0.f,0.f},{0.f,0.f,0.f,0.f},{0.f,0.f,0.f,0.f},{0.f,0.f,0.f,0.f}},
                     {{0.f,0.f,0.f,0.f},{0.f,0.f,0.f,0.f},{0.f,0.f,0.f,0.f},{0.f,0.f,0.f,0.f}}};
  #pragma unroll
  for (int tap = 0; tap < 9; tap++){
    const int dy = tap/3, dx = tap - dy*3;
    const int xp = l15 + dx;
    const int xm = xp & 7;
    short8 b0[4], b1[4];
    #pragma unroll
    for (int nt = 0; nt < 4; nt++){
      const unsigned short* bp = Bw + (((size_t)tap*64 + nt*16 + l15)*64 + quad*8);
      b0[nt] = *(const short8*)bp;
      b1[nt] = *(const short8*)(bp + 32);
    }
    #pragma unroll
    for (int rr = 0; rr < 2; rr++){
      int yp = 2*w + rr + dy;
      int abase = (yp*18 + xp)*64;
      short8 aL = *(const short8*)&smemA[abase + ((quad    ) ^ xm)*8];
      short8 aH = *(const short8*)&smemA[abase + ((4 + quad) ^ xm)*8];
      #pragma unroll
      for (int nt = 0; nt < 4; nt++)
        acc[rr][nt] = __builtin_amdgcn_mfma_f32_16x16x32_bf16(aL, b0[nt], acc[rr][nt], 0,0,0);
      #pragma unroll
      for (int nt = 0; nt < 4; nt++)
        acc[rr][nt] = __builtin_amdgcn_mfma_f32_16x16x32_bf16(aH, b1[nt], acc[rr][nt], 0,0,0);
    }
  }

  #pragma unroll
  for (int nt = 0; nt < 4; nt++){
    int oc = nt*16 + l15;
    float bv = bias[oc];
    float s = 0.f, q = 0.f;
    #pragma unroll
    for (int rr = 0; rr < 2; rr++){
      int y = y0 + 2*w + rr;
      size_t rbase = ((size_t)b*NPIX + (size_t)y*CONVW)*64;
      #pragma unroll
      for (int r = 0; r < 4; r++){
        float v = acc[rr][nt][r] + bv;
        int x = x0 + quad*4 + r;
        out[rbase + (size_t)x*64 + oc] = v;
        s += v; q += v*v;
      }
    }
    s += __shfl_xor(s, 16); s += __shfl_xor(s, 32);
    q += __shfl_xor(q, 16); q += __shfl_xor(q, 32);
    if (quad == 0){ atomicAdd(&sA[oc], s); atomicAdd(&sQ[oc], q); }
  }
  __syncthreads();
  if (tid < 64){
    atomicAdd(&st[shad*128 + tid], sA[tid]);
    atomicAdd(&st[shad*128 + 64 + tid], sQ[tid]);
  }
}

// ---- head 1x1: fused BN/relu of last conv layer
extern "C" __global__ void __launch_bounds__(256) k_head(const float* __restrict__ in,
    const float* __restrict__ stin, const float* __restrict__ g, const float* __restrict__ be,
    const float* __restrict__ hw, const float* __restrict__ hb, float* __restrict__ outp){
  __shared__ float bnsc[64], bnsh[64];
  int tid = threadIdx.x;
  if (tid < 64){
    const float invN = 1.f/(float)(BATCH*NPIX);
    float m = 0.f, q = 0.f;
    #pragma unroll
    for (int s=0;s<SHAD;s++){ m += stin[s*128+tid]; q += stin[s*128+64+tid]; }
    m *= invN;
    float va = q*invN - m*m;
    float sc = g[tid]*rsqrtf(va + 1e-5f);
    bnsc[tid] = sc; bnsh[tid] = be[tid] - m*sc;
  }
  __syncthreads();
  int i = blockIdx.x*256 + tid;
  if (i >= BATCH*NPIX) return;
  const float* base = in + (size_t)i*64;
  float a0 = hb[0], a1 = hb[1], a2 = hb[2];
  #pragma unroll
  for (int jb = 0; jb < 16; jb++){
    float4 v = *(const float4*)(base + jb*4);
    float vv[4] = {v.x, v.y, v.z, v.w};
    #pragma unroll
    for (int e = 0; e < 4; e++){
      int ic = jb*4 + e;
      float h = fmaxf(vv[e]*bnsc[ic] + bnsh[ic], 0.f);
      a0 += h*hw[ic]; a1 += h*hw[64+ic]; a2 += h*hw[128+ic];
    }
  }
  size_t o = (size_t)i*3;
  outp[o+0] = a0; outp[o+1] = a1; outp[o+2] = a2;
}

extern "C" void kernel_launch(void* const* d_in, const int* in_sizes, int n_in,
                              void* d_out, int out_size, void* d_ws, size_t ws_size,
                              hipStream_t stream){
  (void)in_sizes; (void)n_in; (void)out_size;
  const float* pts   = (const float*)d_in[0];
  const float* w1    = (const float*)d_in[1];
  const float* g1    = (const float*)d_in[2];
  const float* b1    = (const float*)d_in[3];
  const float* w2    = (const float*)d_in[4];
  const float* g2    = (const float*)d_in[5];
  const float* b2    = (const float*)d_in[6];
  const float* w3    = (const float*)d_in[7];
  const float* g3    = (const float*)d_in[8];
  const float* b3    = (const float*)d_in[9];
  const float* cs_w  = (const float*)d_in[10];
  const float* cs_b  = (const float*)d_in[11];
  const float* cs_g  = (const float*)d_in[12];
  const float* cs_be = (const float*)d_in[13];
  const float* rpn_w = (const float*)d_in[14];
  const float* rpn_b = (const float*)d_in[15];
  const float* rpn_g = (const float*)d_in[16];
  const float* rpn_be= (const float*)d_in[17];
  const float* hw    = (const float*)d_in[18];
  const float* hb    = (const float*)d_in[19];

  char* ws = (char*)d_ws;
  size_t off = 0;
  auto alloc = [&](size_t bytes)->char*{
    char* p = ws + off; off += (bytes + 255) & ~(size_t)255; return p;
  };
  // ---- zero region (single memset) ----
  int*   cellcnt = (int*)  alloc((size_t)BATCH*NCELL*4);
  int*   vv      = (int*)  alloc((size_t)NVOX*4);
  int*   cnt     = (int*)  alloc((size_t)NVOX*4);
  int*   fill    = (int*)  alloc((size_t)NVOX*4);
  float* stats   = (float*)alloc(131072);
  size_t zbytes  = off;
  // ---- no-init region ----
  int*   slotmap = (int*)  alloc((size_t)BATCH*NCELL*4);
  int*   blks    = (int*)  alloc((size_t)BATCH*512*4);
  int*   plist   = (int*)  alloc((size_t)NVOX*PMAX*4);      // conv alias start, 5.12MB
  float* pvox    = (float*)alloc((size_t)NVOX*PMAX*16);     // 20.48MB
  float* mean    = (float*)alloc((size_t)NVOX*16);          // 0.64MB
  float* K2buf   = (float*)alloc((size_t)NVOX*64*4);        // 10.24MB (alias end)
  unsigned* bevk = (unsigned*)alloc((size_t)NELEM*4);       // 18.02MB (uint keys)
  unsigned short* Bw = (unsigned short*)alloc((size_t)5*36864*2);
  if (off > ws_size) return;

  float* st1 = stats;            // [32][64]
  float* st2 = stats + 2048;     // [32][128]
  float* st3 = stats + 6144;     // [32][128]
  float* stc = stats + 10240;    // 5 x [32][128]

  // conv ping-pong aliases plist..K2buf (36.49MB contiguous, dead before convs)
  float* convA = (float*)plist;
  float* convB = (float*)((char*)plist + 18022400);

  hipMemsetAsync(ws, 0, zbytes, stream);

  k_count <<<(BATCH*NPTS+255)/256, 256, 0, stream>>>(pts, cellcnt);
  k_blkcount<<<dim3(SCAN_NB,BATCH), 256, 0, stream>>>(cellcnt, blks);
  k_scan  <<<BATCH, 512, 0, stream>>>(blks);
  k_assign<<<dim3(SCAN_NB,BATCH), 256, 0, stream>>>(cellcnt, blks, slotmap, vv, cnt);
  k_fill  <<<(BATCH*NPTS+255)/256, 256, 0, stream>>>(pts, slotmap, fill, plist);
  k_binit <<<(NELEM/4+255)/256, 256, 0, stream>>>(bevk);
  k_feat  <<<NVOX/8, 256, 0, stream>>>(pts, cnt, plist, pvox, mean);

  k_p1<<<PGRID, 256, 0, stream>>>(pvox, mean, cnt, w1, st1);
  k_p2<<<PGRID, 256, 0, stream>>>(pvox, mean, cnt, w1, g1, b1, w2, st1, st2, K2buf);
  k_wprep<<<(5*36864+255)/256, 256, 0, stream>>>(cs_w, rpn_w, Bw);
  k_p3<<<PGRID, 256, 0, stream>>>(pvox, mean, cnt, vv, w2, g2, b2, w3, g3, st2, st3,
                                  K2buf, bevk);

  const float* bptr[5]  = {cs_b, cs_b+64,   rpn_b, rpn_b+64,   rpn_b+128};
  const float* gptr[5]  = {cs_g, cs_g+64,   rpn_g, rpn_g+64,   rpn_g+128};
  const float* beptr[5] = {cs_be,cs_be+64,  rpn_be,rpn_be+64,  rpn_be+128};
  const float* srcs[5]  = {(const float*)bevk, convA, convB, convA, convB};
  float*       dsts[5]  = {convA, convB, convA, convB, convA};
  dim3 cgrid(CONVW/16, CONVH/CTH, BATCH);
  for (int ll = 0; ll < 5; ll++){
    const float* stin = (ll == 0) ? st3 : (stc + (ll-1)*4096);
    const float* gg   = (ll == 0) ? g3 : gptr[ll-1];
    const float* bb   = (ll == 0) ? b3 : beptr[ll-1];
    float eps  = (ll == 0) ? 1e-3f : 1e-5f;
    float invN = (ll == 0) ? 1.f/(float)NPFN : 1.f/(float)(BATCH*NPIX);
    k_conv<<<cgrid, 256, 0, stream>>>(srcs[ll], stin, gg, bb, eps, invN, (ll==0)?1:0,
                                      Bw + (size_t)ll*36864, bptr[ll], dsts[ll],
                                      stc + ll*4096);
  }
  k_head<<<(BATCH*NPIX+255)/256, 256, 0, stream>>>(convA, stc + 4*4096, gptr[4], beptr[4],
                                                   hw, hb, (float*)d_out);
}

// Round 12
// 319.998 us; speedup vs baseline: 1.0162x; 1.0162x over previous
//
#include <hip/hip_runtime.h>

// Round 12: (1) PGRID reverted to 1024 (2048 A/B-regressed k_p3 by 13us),
// (2) dual-voxel + pair-prefetch in p2/p3 (2 independent chains/wave),
// (3) bf16 conv chain (conv outputs stored bf16 pre-BN; stats stay f32).
// p4-elimination (uint-key atomicMax scatter) kept from round 11.

#define BATCH 2
#define NPTS 100000
#define GNX 176
#define GNY 200
#define GNZ 10
#define NCELL (GNX*GNY*GNZ)
#define PMAX 32
#define MAXV 20000
#define NVOX (BATCH*MAXV)
#define NPFN (NVOX*PMAX)
#define CONVH 200
#define CONVW 176
#define NPIX (CONVH*CONVW)
#define NELEM (BATCH*NPIX*64)
#define SCAN_NB ((NCELL + 1023)/1024)
#define PGRID 1024
#define SHAD 32
#define KNEGINF 0x007FFFFFu   // key(-inf)

typedef __attribute__((ext_vector_type(8))) short short8;
typedef __attribute__((ext_vector_type(4))) float f32x4;

__device__ __forceinline__ unsigned short f2bf(float f){
  unsigned int u = __float_as_uint(f);
  u = (u + 0x7fffu + ((u >> 16) & 1u)) >> 16;
  return (unsigned short)u;
}
__device__ __forceinline__ float bf2f(unsigned short s){
  return __uint_as_float(((unsigned int)s) << 16);
}

__device__ __forceinline__ int voxel_id(float x, float y, float z){
  int ix = (int)floorf(x / 0.4f);
  int iy = (int)floorf((y + 40.0f) / 0.4f);
  int iz = (int)floorf((z + 3.0f) / 0.4f);
  if (ix < 0 || iy < 0 || iz < 0 || ix >= GNX || iy >= GNY || iz >= GNZ) return -1;
  return (ix*GNY + iy)*GNZ + iz;
}

extern "C" __global__ void k_count(const float* __restrict__ pts, int* __restrict__ cellcnt){
  int i = blockIdx.x*256 + threadIdx.x;
  if (i >= BATCH*NPTS) return;
  const float* q = pts + (size_t)i*4;
  int vid = voxel_id(q[0], q[1], q[2]);
  if (vid < 0) return;
  int b = i / NPTS;
  atomicAdd(&cellcnt[b*NCELL + vid], 1);
}

extern "C" __global__ void __launch_bounds__(256) k_blkcount(const int* __restrict__ cellcnt,
                                                             int* __restrict__ blks){
  int b = blockIdx.y, blk = blockIdx.x, t = threadIdx.x;
  int base = blk*1024 + t*4;
  int s = 0;
  #pragma unroll
  for (int i=0;i<4;i++){ int c = base+i; if (c < NCELL) s += (cellcnt[b*NCELL+c] > 0); }
  #pragma unroll
  for (int m=32;m>=1;m>>=1) s += __shfl_xor(s, m);
  __shared__ int red[4];
  if ((t&63)==0) red[t>>6] = s;
  __syncthreads();
  if (t==0) blks[b*512+blk] = red[0]+red[1]+red[2]+red[3];
}

extern "C" __global__ void __launch_bounds__(512) k_scan(int* __restrict__ blks){
  int b = blockIdx.x, t = threadIdx.x;
  __shared__ int l[512];
  int orig = (t < SCAN_NB) ? blks[b*512+t] : 0;
  l[t] = orig;
  __syncthreads();
  for (int o=1;o<512;o<<=1){
    int v = (t>=o) ? l[t-o] : 0;
    __syncthreads();
    l[t] += v;
    __syncthreads();
  }
  if (t < SCAN_NB) blks[b*512+t] = l[t] - orig;   // exclusive
}

extern "C" __global__ void __launch_bounds__(256) k_assign(const int* __restrict__ cellcnt,
    const int* __restrict__ blks, int* __restrict__ slotmap, int* __restrict__ vv,
    int* __restrict__ cnt){
  int b = blockIdx.y, blk = blockIdx.x, t = threadIdx.x;
  int base = blk*1024 + t*4;
  int flag[4]; int s = 0;
  #pragma unroll
  for (int i=0;i<4;i++){
    int c = base+i;
    flag[i] = (c < NCELL) ? (cellcnt[b*NCELL+c] > 0) : 0;
    s += flag[i];
  }
  __shared__ int lds[256];
  lds[t] = s; __syncthreads();
  for (int o=1;o<256;o<<=1){
    int v = (t>=o) ? lds[t-o] : 0;
    __syncthreads();
    lds[t] += v;
    __syncthreads();
  }
  int run = blks[b*512+blk] + (lds[t]-s);
  #pragma unroll
  for (int i=0;i<4;i++){
    int c = base+i;
    if (c >= NCELL) break;
    int sm = -1;
    if (flag[i]){
      if (run < MAXV){
        sm = run;
        vv[b*MAXV+run]  = c;
        cnt[b*MAXV+run] = min(cellcnt[b*NCELL+c], PMAX);
      }
      run++;
    }
    slotmap[b*NCELL+c] = sm;
  }
}

extern "C" __global__ void k_fill(const float* __restrict__ pts, const int* __restrict__ slotmap,
                                  int* __restrict__ fill, int* __restrict__ plist){
  int i = blockIdx.x*256 + threadIdx.x;
  if (i >= BATCH*NPTS) return;
  const float* q = pts + (size_t)i*4;
  int vid = voxel_id(q[0], q[1], q[2]);
  if (vid < 0) return;
  int b = i / NPTS;
  int slot = slotmap[b*NCELL+vid];
  if (slot < 0) return;
  int pos = atomicAdd(&fill[b*MAXV+slot], 1);
  if (pos < PMAX) plist[((size_t)b*MAXV+slot)*PMAX + pos] = i - b*NPTS;
}

// gather sorted points into pvox [NVOX][32] float4 + per-voxel mean [NVOX] float4
extern "C" __global__ void __launch_bounds__(256) k_feat(const float* __restrict__ pts,
    const int* __restrict__ cnt, const int* __restrict__ plist,
    float* __restrict__ pvox, float* __restrict__ mean){
  int g  = threadIdx.x >> 5;
  int fv = blockIdx.x*8 + g;
  int p  = threadIdx.x & 31;
  int b  = fv / MAXV;
  __shared__ int lst[8][32];
  int c = cnt[fv];
  if (p < c) lst[g][p] = plist[(size_t)fv*PMAX + p];
  __syncthreads();
  if (p == 0){
    for (int i=1;i<c;i++){
      int key = lst[g][i]; int j = i-1;
      while (j >= 0 && lst[g][j] > key){ lst[g][j+1] = lst[g][j]; j--; }
      lst[g][j+1] = key;
    }
  }
  __syncthreads();
  float4 pt = make_float4(0.f,0.f,0.f,0.f);
  if (p < c) pt = *(const float4*)(pts + ((size_t)b*NPTS + lst[g][p])*4);
  float sx = pt.x, sy = pt.y, sz = pt.z;
  #pragma unroll
  for (int m=16;m>=1;m>>=1){
    sx += __shfl_xor(sx, m, 32); sy += __shfl_xor(sy, m, 32); sz += __shfl_xor(sz, m, 32);
  }
  float cd = (float)max(c, 1);
  if (p < c) *(float4*)(pvox + ((size_t)fv*32 + p)*4) = pt;
  if (p == 0) *(float4*)(mean + (size_t)fv*4) = make_float4(sx/cd, sy/cd, sz/cd, 0.f);
}

// BEV key init: every element = key(-inf)
extern "C" __global__ void k_binit(unsigned* __restrict__ bev){
  int i = blockIdx.x*256 + threadIdx.x;
  if (i*4 >= NELEM) return;
  uint4 v = make_uint4(KNEGINF, KNEGINF, KNEGINF, KNEGINF);
  ((uint4*)bev)[i] = v;
}

#define IN7(pt, mn) {pt.x, pt.y, pt.z, pt.w, pt.x-mn.x, pt.y-mn.y, pt.z-mn.z}

// ============ PFN phases ============
extern "C" __global__ void __launch_bounds__(256) k_p1(const float* __restrict__ pvox,
    const float* __restrict__ mean, const int* __restrict__ cnt,
    const float* __restrict__ w1, float* __restrict__ st){
  __shared__ float w1L[224];
  __shared__ float sred[64];
  int tid = threadIdx.x;
  if (tid < 56) ((float4*)w1L)[tid] = ((const float4*)w1)[tid];
  if (tid < 64) sred[tid] = 0.f;
  __syncthreads();
  int w = tid>>6, lane = tid&63, c = lane&31, half = lane>>5;
  const int STR = PGRID*4;
  int fv = blockIdx.x*4 + w;
  int c_n = 0;
  float4 mn_n = make_float4(0.f,0.f,0.f,0.f), pA_n = mn_n;
  if (fv < NVOX){
    c_n  = cnt[fv];
    mn_n = *(const float4*)(mean + (size_t)fv*4);
    pA_n = *(const float4*)(pvox + ((size_t)fv*32 + half)*4);
  }
  float S=0.f, Q=0.f;
  while (fv < NVOX){
    const int fvc = fv;
    const int c_ = c_n;
    const float4 mn = mn_n, pA = pA_n;
    fv += STR;
    if (fv < NVOX){
      c_n  = cnt[fv];
      mn_n = *(const float4*)(mean + (size_t)fv*4);
      pA_n = *(const float4*)(pvox + ((size_t)fv*32 + half)*4);
    }
    {
      float in[7] = IN7(pA, mn);
      float v = 0.f;
      #pragma unroll
      for (int k=0;k<7;k++) v += in[k]*w1L[k*32+c];
      if (half < c_){ S += v; Q += v*v; }
    }
    for (int p = half+2; p < c_; p += 2){
      float4 pt = *(const float4*)(pvox + ((size_t)fvc*32+p)*4);
      float in[7] = IN7(pt, mn);
      float v = 0.f;
      #pragma unroll
      for (int k=0;k<7;k++) v += in[k]*w1L[k*32+c];
      S += v; Q += v*v;
    }
  }
  S += __shfl_xor(S,32); Q += __shfl_xor(Q,32);
  if (half==0){ atomicAdd(&sred[c],S); atomicAdd(&sred[32+c],Q); }
  __syncthreads();
  if (tid<64) atomicAdd(&st[(blockIdx.x&(SHAD-1))*64+tid], sred[tid]);
}

// p2: dual-voxel per wave-iteration + pair prefetch.
extern "C" __global__ void __launch_bounds__(256) k_p2(const float* __restrict__ pvox,
    const float* __restrict__ mean, const int* __restrict__ cnt,
    const float* __restrict__ w1, const float* __restrict__ g1, const float* __restrict__ b1,
    const float* __restrict__ w2, const float* __restrict__ st1, float* __restrict__ st2,
    float* __restrict__ K2buf){
  __shared__ float w1L[224];
  __shared__ float w2L[2496];
  __shared__ float sred[128];
  int tid = threadIdx.x;
  if (tid < 56) ((float4*)w1L)[tid] = ((const float4*)w1)[tid];
  for (int i=tid;i<624;i+=256) ((float4*)w2L)[i] = ((const float4*)w2)[i];
  if (tid < 128) sred[tid] = 0.f;
  __syncthreads();
  int w = tid>>6, lane = tid&63, c1 = lane&31;
  const float invN = 1.f/(float)NPFN;
  float m1=0.f, v1s=0.f;
  #pragma unroll
  for (int s=0;s<SHAD;s++){ m1 += st1[s*64+c1]; v1s += st1[s*64+32+c1]; }
  m1 *= invN; v1s = v1s*invN - m1*m1;
  float sc1 = g1[c1]*rsqrtf(v1s + 1e-3f);
  float sh1 = b1[c1] - m1*sc1;

  auto pt7 = [&](const float4& pt, const float4& mn, bool act,
                 float& vm, float& sa, float& sq){
    float in[7] = IN7(pt, mn);
    float v1 = 0.f, a2 = 0.f;
    #pragma unroll
    for (int k=0;k<7;k++){ v1 += in[k]*w1L[k*32+c1]; a2 += in[k]*w2L[k*64+lane]; }
    if (act){ vm = fmaxf(vm, v1*sc1 + sh1); sa += a2; sq += a2*a2; }
  };

  const int STR = PGRID*8;
  int fv = blockIdx.x*8 + w*2;
  const float4 z = make_float4(0.f,0.f,0.f,0.f);
  int cA_n=0, cB_n=0;
  float4 mnA_n=z, p0A_n=z, p1A_n=z, mnB_n=z, p0B_n=z, p1B_n=z;
  if (fv < NVOX){
    cA_n  = cnt[fv];   cB_n  = cnt[fv+1];
    mnA_n = *(const float4*)(mean + (size_t)fv*4);
    mnB_n = *(const float4*)(mean + (size_t)(fv+1)*4);
    p0A_n = *(const float4*)(pvox + ((size_t)fv*32+0)*4);
    p1A_n = *(const float4*)(pvox + ((size_t)fv*32+1)*4);
    p0B_n = *(const float4*)(pvox + ((size_t)(fv+1)*32+0)*4);
    p1B_n = *(const float4*)(pvox + ((size_t)(fv+1)*32+1)*4);
  }
  float S = 0.f, Q = 0.f;
  while (fv < NVOX){
    const int fvA = fv, fvB = fv+1;
    const int cA = cA_n, cB = cB_n;
    const float4 mnA=mnA_n, p0A=p0A_n, p1A=p1A_n, mnB=mnB_n, p0B=p0B_n, p1B=p1B_n;
    fv += STR;
    if (fv < NVOX){
      cA_n  = cnt[fv];   cB_n  = cnt[fv+1];
      mnA_n = *(const float4*)(mean + (size_t)fv*4);
      mnB_n = *(const float4*)(mean + (size_t)(fv+1)*4);
      p0A_n = *(const float4*)(pvox + ((size_t)fv*32+0)*4);
      p1A_n = *(const float4*)(pvox + ((size_t)fv*32+1)*4);
      p0B_n = *(const float4*)(pvox + ((size_t)(fv+1)*32+0)*4);
      p1B_n = *(const float4*)(pvox + ((size_t)(fv+1)*32+1)*4);
    }
    float vmA=0.f, saA=0.f, sqA=0.f, vmB=0.f, saB=0.f, sqB=0.f;
    pt7(p0A, mnA, cA>0, vmA, saA, sqA);
    pt7(p0B, mnB, cB>0, vmB, saB, sqB);
    pt7(p1A, mnA, cA>1, vmA, saA, sqA);
    pt7(p1B, mnB, cB>1, vmB, saB, sqB);
    for (int p = 2; p < cA; p++){
      float4 pt = *(const float4*)(pvox + ((size_t)fvA*32+p)*4);
      pt7(pt, mnA, true, vmA, saA, sqA);
    }
    for (int p = 2; p < cB; p++){
      float4 pt = *(const float4*)(pvox + ((size_t)fvB*32+p)*4);
      pt7(pt, mnB, true, vmB, saB, sqB);
    }
    float a0=0.f,a1=0.f,a2=0.f,a3=0.f, b0=0.f,b1=0.f,b2=0.f,b3=0.f;
    #pragma unroll
    for (int j=0;j<32;j+=4){
      a0 += __shfl(vmA, j  )*w2L[(7+j )*64+lane];
      b0 += __shfl(vmB, j  )*w2L[(7+j )*64+lane];
      a1 += __shfl(vmA, j+1)*w2L[(8+j )*64+lane];
      b1 += __shfl(vmB, j+1)*w2L[(8+j )*64+lane];
      a2 += __shfl(vmA, j+2)*w2L[(9+j )*64+lane];
      b2 += __shfl(vmB, j+2)*w2L[(9+j )*64+lane];
      a3 += __shfl(vmA, j+3)*w2L[(10+j)*64+lane];
      b3 += __shfl(vmB, j+3)*w2L[(10+j)*64+lane];
    }
    float KA = (a0+a1)+(a2+a3);
    float KB = (b0+b1)+(b2+b3);
    if (cA) K2buf[(size_t)fvA*64 + lane] = KA;
    if (cB) K2buf[(size_t)fvB*64 + lane] = KB;
    S += (float)PMAX*(KA+KB) + saA + saB;
    Q += (float)PMAX*(KA*KA+KB*KB) + sqA + sqB + 2.f*(KA*saA + KB*saB);
  }
  atomicAdd(&sred[lane], S); atomicAdd(&sred[64+lane], Q);
  __syncthreads();
  if (tid < 128) atomicAdd(&st2[(blockIdx.x&(SHAD-1))*128 + tid], sred[tid]);
}

// p3: dual-voxel + pair prefetch; scatters raw extreme into BEV (uint key max).
extern "C" __global__ void __launch_bounds__(256) k_p3(const float* __restrict__ pvox,
    const float* __restrict__ mean, const int* __restrict__ cnt, const int* __restrict__ vv,
    const float* __restrict__ w2, const float* __restrict__ g2, const float* __restrict__ b2,
    const float* __restrict__ w3, const float* __restrict__ g3,
    const float* __restrict__ st2, float* __restrict__ st3,
    const float* __restrict__ K2buf, unsigned* __restrict__ bev){
  __shared__ float w2L[2496];
  __shared__ float w3L[4544];
  __shared__ float sred[128];
  int tid = threadIdx.x;
  for (int i=tid;i<624;i+=256)  ((float4*)w2L)[i] = ((const float4*)w2)[i];
  for (int i=tid;i<1136;i+=256) ((float4*)w3L)[i] = ((const float4*)w3)[i];
  if (tid < 128) sred[tid] = 0.f;
  __syncthreads();
  int w = tid>>6, lane = tid&63;
  const float invN = 1.f/(float)NPFN;
  float m2=0.f, v2s=0.f;
  #pragma unroll
  for (int s=0;s<SHAD;s++){ m2 += st2[s*128+lane]; v2s += st2[s*128+64+lane]; }
  m2 *= invN; v2s = v2s*invN - m2*m2;
  float sc2 = g2[lane]*rsqrtf(v2s + 1e-3f);
  float sh2 = b2[lane] - m2*sc2;
  bool pickmax = (g3[lane] >= 0.f);

  auto pt7 = [&](const float4& pt, const float4& mn, bool act, float K2,
                 float& vm, float& sa, float& sq, float& amx, float& amn){
    float in[7] = IN7(pt, mn);
    float a2 = 0.f, a3 = 0.f;
    #pragma unroll
    for (int k=0;k<7;k++){ a2 += in[k]*w2L[k*64+lane]; a3 += in[k]*w3L[k*64+lane]; }
    if (act){
      vm = fmaxf(vm, (a2+K2)*sc2 + sh2);
      sa += a3; sq += a3*a3;
      amx = fmaxf(amx, a3); amn = fminf(amn, a3);
    }
  };
  auto scat = [&](int fvx, int vid, float raw){
    if (!pickmax) raw = -raw;
    unsigned u = __float_as_uint(raw);
    unsigned key = (u & 0x80000000u) ? ~u : (u | 0x80000000u);
    int bb = fvx / MAXV;
    int cx = vid / (GNY*GNZ);
    int cy = (vid / GNZ) % GNY;
    atomicMax(bev + (((size_t)bb*NPIX + (size_t)cy*CONVW + cx)*64) + lane, key);
  };

  const int STR = PGRID*8;
  int fv = blockIdx.x*8 + w*2;
  const float4 z = make_float4(0.f,0.f,0.f,0.f);
  int cA_n=0, cB_n=0, vvA_n=0, vvB_n=0;
  float K2A_n=0.f, K2B_n=0.f;
  float4 mnA_n=z, p0A_n=z, p1A_n=z, mnB_n=z, p0B_n=z, p1B_n=z;
  if (fv < NVOX){
    cA_n  = cnt[fv];   cB_n  = cnt[fv+1];
    vvA_n = vv[fv];    vvB_n = vv[fv+1];
    K2A_n = K2buf[(size_t)fv*64 + lane];
    K2B_n = K2buf[(size_t)(fv+1)*64 + lane];
    mnA_n = *(const float4*)(mean + (size_t)fv*4);
    mnB_n = *(const float4*)(mean + (size_t)(fv+1)*4);
    p0A_n = *(const float4*)(pvox + ((size_t)fv*32+0)*4);
    p1A_n = *(const float4*)(pvox + ((size_t)fv*32+1)*4);
    p0B_n = *(const float4*)(pvox + ((size_t)(fv+1)*32+0)*4);
    p1B_n = *(const float4*)(pvox + ((size_t)(fv+1)*32+1)*4);
  }
  float S = 0.f, Q = 0.f;
  while (fv < NVOX){
    const int fvA = fv, fvB = fv+1;
    const int cA = cA_n, cB = cB_n, vidA = vvA_n, vidB = vvB_n;
    const float K2A = K2A_n, K2B = K2B_n;
    const float4 mnA=mnA_n, p0A=p0A_n, p1A=p1A_n, mnB=mnB_n, p0B=p0B_n, p1B=p1B_n;
    fv += STR;
    if (fv < NVOX){
      cA_n  = cnt[fv];   cB_n  = cnt[fv+1];
      vvA_n = vv[fv];    vvB_n = vv[fv+1];
      K2A_n = K2buf[(size_t)fv*64 + lane];
      K2B_n = K2buf[(size_t)(fv+1)*64 + lane];
      mnA_n = *(const float4*)(mean + (size_t)fv*4);
      mnB_n = *(const float4*)(mean + (size_t)(fv+1)*4);
      p0A_n = *(const float4*)(pvox + ((size_t)fv*32+0)*4);
      p1A_n = *(const float4*)(pvox + ((size_t)fv*32+1)*4);
      p0B_n = *(const float4*)(pvox + ((size_t)(fv+1)*32+0)*4);
      p1B_n = *(const float4*)(pvox + ((size_t)(fv+1)*32+1)*4);
    }
    float vmA=0.f, saA=0.f, sqA=0.f, amxA=-3.4e38f, amnA=3.4e38f;
    float vmB=0.f, saB=0.f, sqB=0.f, amxB=-3.4e38f, amnB=3.4e38f;
    pt7(p0A, mnA, cA>0, K2A, vmA, saA, sqA, amxA, amnA);
    pt7(p0B, mnB, cB>0, K2B, vmB, saB, sqB, amxB, amnB);
    pt7(p1A, mnA, cA>1, K2A, vmA, saA, sqA, amxA, amnA);
    pt7(p1B, mnB, cB>1, K2B, vmB, saB, sqB, amxB, amnB);
    for (int p = 2; p < cA; p++){
      float4 pt = *(const float4*)(pvox + ((size_t)fvA*32+p)*4);
      pt7(pt, mnA, true, K2A, vmA, saA, sqA, amxA, amnA);
    }
    for (int p = 2; p < cB; p++){
      float4 pt = *(const float4*)(pvox + ((size_t)fvB*32+p)*4);
      pt7(pt, mnB, true, K2B, vmB, saB, sqB, amxB, amnB);
    }
    float a0=0.f,a1=0.f,a2=0.f,a3=0.f, b0=0.f,b1=0.f,b2=0.f,b3=0.f;
    #pragma unroll
    for (int j=0;j<64;j+=4){
      a0 += __shfl(vmA, j  )*w3L[(7+j )*64+lane];
      b0 += __shfl(vmB, j  )*w3L[(7+j )*64+lane];
      a1 += __shfl(vmA, j+1)*w3L[(8+j )*64+lane];
      b1 += __shfl(vmB, j+1)*w3L[(8+j )*64+lane];
      a2 += __shfl(vmA, j+2)*w3L[(9+j )*64+lane];
      b2 += __shfl(vmB, j+2)*w3L[(9+j )*64+lane];
      a3 += __shfl(vmA, j+3)*w3L[(10+j)*64+lane];
      b3 += __shfl(vmB, j+3)*w3L[(10+j)*64+lane];
    }
    float KA = (a0+a1)+(a2+a3);
    float KB = (b0+b1)+(b2+b3);
    if (cA) scat(fvA, vidA, (pickmax ? amxA : amnA) + KA);
    if (cB) scat(fvB, vidB, (pickmax ? amxB : amnB) + KB);
    S += (float)PMAX*(KA+KB) + saA + saB;
    Q += (float)PMAX*(KA*KA+KB*KB) + sqA + sqB + 2.f*(KA*saA + KB*saB);
  }
  atomicAdd(&sred[lane], S); atomicAdd(&sred[64+lane], Q);
  __syncthreads();
  if (tid < 128) atomicAdd(&st3[(blockIdx.x&(SHAD-1))*128 + tid], sred[tid]);
}

// ---- weight prepack: [oc][ic][3][3] f32 -> [tap][oc][ic] bf16, 5 layers
extern "C" __global__ void k_wprep(const float* __restrict__ cs_w, const float* __restrict__ rpn_w,
                                   unsigned short* __restrict__ Bw){
  int i = blockIdx.x*256 + threadIdx.x;
  if (i >= 5*36864) return;
  int l = i/36864, r = i - l*36864;
  int tap = r >> 12, oc = (r >> 6) & 63, ic = r & 63;
  const float* src = (l < 2) ? (cs_w + (size_t)l*36864) : (rpn_w + (size_t)(l-2)*36864);
  Bw[i] = f2bf(src[((size_t)oc*64 + ic)*9 + tap]);
}

// ---- conv3x3: implicit GEMM, bf16 MFMA. Tile 16x*8y, fused BN/relu on
//      staging. Layer 0 reads uint-key BEV (inK); others read bf16 (inH).
//      Output stored bf16 (pre-BN raw + bias); stats from f32 acc.
#define CTH 8
extern "C" __global__ void __launch_bounds__(256) k_conv(const unsigned* __restrict__ inK,
    const unsigned short* __restrict__ inH,
    const float* __restrict__ stin, const float* __restrict__ g, const float* __restrict__ be,
    float eps, float invN, int raw0,
    const unsigned short* __restrict__ Bw, const float* __restrict__ bias,
    unsigned short* __restrict__ out, float* __restrict__ st){
  const int b  = blockIdx.z;
  const int x0 = blockIdx.x*16, y0 = blockIdx.y*CTH;
  const int tid = threadIdx.x;
  const int w = tid >> 6, l = tid & 63;
  const int l15 = l & 15, quad = l >> 4;
  const int bid = (blockIdx.z*gridDim.y + blockIdx.y)*gridDim.x + blockIdx.x;
  const int shad = bid & (SHAD-1);

  __shared__ unsigned short smemA[(CTH+2)*18*64];
  __shared__ float bnsc[64], bnsh[64];
  __shared__ float sA[64], sQ[64];
  if (tid < 64){
    sA[tid] = 0.f; sQ[tid] = 0.f;
    float m = 0.f, q = 0.f;
    #pragma unroll
    for (int s=0;s<SHAD;s++){ m += stin[s*128+tid]; q += stin[s*128+64+tid]; }
    m *= invN;
    float va = q*invN - m*m;
    float sc = g[tid]*rsqrtf(va + eps);
    bnsc[tid] = sc; bnsh[tid] = be[tid] - m*sc;
  }
  __syncthreads();

  for (int i = tid; i < (CTH+2)*18*8; i += 256){
    int pos = i >> 3, jb = i & 7;
    int yp = pos/18, xp = pos - yp*18;
    int gy = y0 + yp - 1, gx = x0 + xp - 1;
    unsigned short h[8] = {0,0,0,0,0,0,0,0};
    if (gy >= 0 && gy < CONVH && gx >= 0 && gx < CONVW){
      size_t ebase = ((size_t)b*NPIX + (size_t)gy*CONVW + gx)*64 + jb*8;
      float f[8];
      if (raw0){
        uint4 u0 = *(const uint4*)(inK + ebase);
        uint4 u1 = *(const uint4*)(inK + ebase + 4);
        unsigned kk[8] = {u0.x,u0.y,u0.z,u0.w,u1.x,u1.y,u1.z,u1.w};
        #pragma unroll
        for (int k=0;k<8;k++){
          unsigned key = kk[k];
          unsigned u = (key & 0x80000000u) ? (key & 0x7fffffffu) : ~key;
          float v = __uint_as_float(u);
          int c = jb*8 + k;
          if (bnsc[c] < 0.f) v = -v;   // min-channels stored negated
          f[k] = v;
        }
      } else {
        uint4 v4 = *(const uint4*)(inH + ebase);
        unsigned uu[4] = {v4.x, v4.y, v4.z, v4.w};
        #pragma unroll
        for (int e=0;e<4;e++){
          f[e*2]   = bf2f((unsigned short)(uu[e] & 0xffffu));
          f[e*2+1] = bf2f((unsigned short)(uu[e] >> 16));
        }
      }
      #pragma unroll
      for (int k=0;k<8;k++){
        int c = jb*8 + k;
        h[k] = f2bf(fmaxf(f[k]*bnsc[c] + bnsh[c], 0.f));
      }
    }
    int jsw = jb ^ (xp & 7);
    *(uint4*)&smemA[pos*64 + jsw*8] = *(uint4*)h;
  }
  __syncthreads();

  f32x4 acc[2][4] = {{{0.f,0.f,0.f,0.f},{0.f,0.f,0.f,0.f},{0.f,0.f,0.f,0.f},{0.f,0.f,0.f,0.f}},
                     {{0.f,0.f,0.f,0.f},{0.f,0.f,0.f,0.f},{0.f,0.f,0.f,0.f},{0.f,0.f,0.f,0.f}}};
  #pragma unroll
  for (int tap = 0; tap < 9; tap++){
    const int dy = tap/3, dx = tap - dy*3;
    const int xp = l15 + dx;
    const int xm = xp & 7;
    short8 b0[4], b1[4];
    #pragma unroll
    for (int nt = 0; nt < 4; nt++){
      const unsigned short* bp = Bw + (((size_t)tap*64 + nt*16 + l15)*64 + quad*8);
      b0[nt] = *(const short8*)bp;
      b1[nt] = *(const short8*)(bp + 32);
    }
    #pragma unroll
    for (int rr = 0; rr < 2; rr++){
      int yp = 2*w + rr + dy;
      int abase = (yp*18 + xp)*64;
      short8 aL = *(const short8*)&smemA[abase + ((quad    ) ^ xm)*8];
      short8 aH = *(const short8*)&smemA[abase + ((4 + quad) ^ xm)*8];
      #pragma unroll
      for (int nt = 0; nt < 4; nt++)
        acc[rr][nt] = __builtin_amdgcn_mfma_f32_16x16x32_bf16(aL, b0[nt], acc[rr][nt], 0,0,0);
      #pragma unroll
      for (int nt = 0; nt < 4; nt++)
        acc[rr][nt] = __builtin_amdgcn_mfma_f32_16x16x32_bf16(aH, b1[nt], acc[rr][nt], 0,0,0);
    }
  }

  #pragma unroll
  for (int nt = 0; nt < 4; nt++){
    int oc = nt*16 + l15;
    float bv = bias[oc];
    float s = 0.f, q = 0.f;
    #pragma unroll
    for (int rr = 0; rr < 2; rr++){
      int y = y0 + 2*w + rr;
      size_t rbase = ((size_t)b*NPIX + (size_t)y*CONVW)*64;
      #pragma unroll
      for (int r = 0; r < 4; r++){
        float v = acc[rr][nt][r] + bv;
        int x = x0 + quad*4 + r;
        out[rbase + (size_t)x*64 + oc] = f2bf(v);
        s += v; q += v*v;
      }
    }
    s += __shfl_xor(s, 16); s += __shfl_xor(s, 32);
    q += __shfl_xor(q, 16); q += __shfl_xor(q, 32);
    if (quad == 0){ atomicAdd(&sA[oc], s); atomicAdd(&sQ[oc], q); }
  }
  __syncthreads();
  if (tid < 64){
    atomicAdd(&st[shad*128 + tid], sA[tid]);
    atomicAdd(&st[shad*128 + 64 + tid], sQ[tid]);
  }
}

// ---- head 1x1: bf16 in + fused BN/relu of last conv layer
extern "C" __global__ void __launch_bounds__(256) k_head(const unsigned short* __restrict__ in,
    const float* __restrict__ stin, const float* __restrict__ g, const float* __restrict__ be,
    const float* __restrict__ hw, const float* __restrict__ hb, float* __restrict__ outp){
  __shared__ float bnsc[64], bnsh[64];
  int tid = threadIdx.x;
  if (tid < 64){
    const float invN = 1.f/(float)(BATCH*NPIX);
    float m = 0.f, q = 0.f;
    #pragma unroll
    for (int s=0;s<SHAD;s++){ m += stin[s*128+tid]; q += stin[s*128+64+tid]; }
    m *= invN;
    float va = q*invN - m*m;
    float sc = g[tid]*rsqrtf(va + 1e-5f);
    bnsc[tid] = sc; bnsh[tid] = be[tid] - m*sc;
  }
  __syncthreads();
  int i = blockIdx.x*256 + tid;
  if (i >= BATCH*NPIX) return;
  const uint4* p = (const uint4*)(in + (size_t)i*64);
  float a0 = hb[0], a1 = hb[1], a2 = hb[2];
  #pragma unroll
  for (int jb = 0; jb < 8; jb++){
    uint4 u = p[jb];
    unsigned uu[4] = {u.x, u.y, u.z, u.w};
    #pragma unroll
    for (int e = 0; e < 4; e++){
      int ic = jb*8 + e*2;
      float v0 = bf2f((unsigned short)(uu[e] & 0xffffu));
      float v1 = bf2f((unsigned short)(uu[e] >> 16));
      float h0 = fmaxf(v0*bnsc[ic]   + bnsh[ic],   0.f);
      float h1 = fmaxf(v1*bnsc[ic+1] + bnsh[ic+1], 0.f);
      a0 += h0*hw[ic] + h1*hw[ic+1];
      a1 += h0*hw[64+ic] + h1*hw[64+ic+1];
      a2 += h0*hw[128+ic] + h1*hw[128+ic+1];
    }
  }
  size_t o = (size_t)i*3;
  outp[o+0] = a0; outp[o+1] = a1; outp[o+2] = a2;
}

extern "C" void kernel_launch(void* const* d_in, const int* in_sizes, int n_in,
                              void* d_out, int out_size, void* d_ws, size_t ws_size,
                              hipStream_t stream){
  (void)in_sizes; (void)n_in; (void)out_size;
  const float* pts   = (const float*)d_in[0];
  const float* w1    = (const float*)d_in[1];
  const float* g1    = (const float*)d_in[2];
  const float* b1    = (const float*)d_in[3];
  const float* w2    = (const float*)d_in[4];
  const float* g2    = (const float*)d_in[5];
  const float* b2    = (const float*)d_in[6];
  const float* w3    = (const float*)d_in[7];
  const float* g3    = (const float*)d_in[8];
  const float* b3    = (const float*)d_in[9];
  const float* cs_w  = (const float*)d_in[10];
  const float* cs_b  = (const float*)d_in[11];
  const float* cs_g  = (const float*)d_in[12];
  const float* cs_be = (const float*)d_in[13];
  const float* rpn_w = (const float*)d_in[14];
  const float* rpn_b = (const float*)d_in[15];
  const float* rpn_g = (const float*)d_in[16];
  const float* rpn_be= (const float*)d_in[17];
  const float* hw    = (const float*)d_in[18];
  const float* hb    = (const float*)d_in[19];

  char* ws = (char*)d_ws;
  size_t off = 0;
  auto alloc = [&](size_t bytes)->char*{
    char* p = ws + off; off += (bytes + 255) & ~(size_t)255; return p;
  };
  // ---- zero region (single memset) ----
  int*   cellcnt = (int*)  alloc((size_t)BATCH*NCELL*4);
  int*   vv      = (int*)  alloc((size_t)NVOX*4);
  int*   cnt     = (int*)  alloc((size_t)NVOX*4);
  int*   fill    = (int*)  alloc((size_t)NVOX*4);
  float* stats   = (float*)alloc(131072);
  size_t zbytes  = off;
  // ---- no-init region ----
  int*   slotmap = (int*)  alloc((size_t)BATCH*NCELL*4);
  int*   blks    = (int*)  alloc((size_t)BATCH*512*4);
  int*   plist   = (int*)  alloc((size_t)NVOX*PMAX*4);      // conv alias start, 5.12MB
  float* pvox    = (float*)alloc((size_t)NVOX*PMAX*16);     // 20.48MB
  float* mean    = (float*)alloc((size_t)NVOX*16);          // 0.64MB
  float* K2buf   = (float*)alloc((size_t)NVOX*64*4);        // 10.24MB (alias end)
  unsigned* bevk = (unsigned*)alloc((size_t)NELEM*4);       // 18.02MB (uint keys)
  unsigned short* Bw = (unsigned short*)alloc((size_t)5*36864*2);
  if (off > ws_size) return;

  float* st1 = stats;            // [32][64]
  float* st2 = stats + 2048;     // [32][128]
  float* st3 = stats + 6144;     // [32][128]
  float* stc = stats + 10240;    // 5 x [32][128]

  // conv ping-pong (bf16, 9.01MB each) aliases plist..pvox (dead before convs)
  unsigned short* convA = (unsigned short*)plist;
  unsigned short* convB = (unsigned short*)((char*)plist + 9011200);

  hipMemsetAsync(ws, 0, zbytes, stream);

  k_count <<<(BATCH*NPTS+255)/256, 256, 0, stream>>>(pts, cellcnt);
  k_blkcount<<<dim3(SCAN_NB,BATCH), 256, 0, stream>>>(cellcnt, blks);
  k_scan  <<<BATCH, 512, 0, stream>>>(blks);
  k_assign<<<dim3(SCAN_NB,BATCH), 256, 0, stream>>>(cellcnt, blks, slotmap, vv, cnt);
  k_fill  <<<(BATCH*NPTS+255)/256, 256, 0, stream>>>(pts, slotmap, fill, plist);
  k_binit <<<(NELEM/4+255)/256, 256, 0, stream>>>(bevk);
  k_feat  <<<NVOX/8, 256, 0, stream>>>(pts, cnt, plist, pvox, mean);

  k_p1<<<PGRID, 256, 0, stream>>>(pvox, mean, cnt, w1, st1);
  k_p2<<<PGRID, 256, 0, stream>>>(pvox, mean, cnt, w1, g1, b1, w2, st1, st2, K2buf);
  k_wprep<<<(5*36864+255)/256, 256, 0, stream>>>(cs_w, rpn_w, Bw);
  k_p3<<<PGRID, 256, 0, stream>>>(pvox, mean, cnt, vv, w2, g2, b2, w3, g3, st2, st3,
                                  K2buf, bevk);

  const float* bptr[5]  = {cs_b, cs_b+64,   rpn_b, rpn_b+64,   rpn_b+128};
  const float* gptr[5]  = {cs_g, cs_g+64,   rpn_g, rpn_g+64,   rpn_g+128};
  const float* beptr[5] = {cs_be,cs_be+64,  rpn_be,rpn_be+64,  rpn_be+128};
  const unsigned short* srcs[5] = {nullptr, convA, convB, convA, convB};
  unsigned short*       dsts[5] = {convA, convB, convA, convB, convA};
  dim3 cgrid(CONVW/16, CONVH/CTH, BATCH);
  for (int ll = 0; ll < 5; ll++){
    const float* stin = (ll == 0) ? st3 : (stc + (ll-1)*4096);
    const float* gg   = (ll == 0) ? g3 : gptr[ll-1];
    const float* bb   = (ll == 0) ? b3 : beptr[ll-1];
    float eps  = (ll == 0) ? 1e-3f : 1e-5f;
    float invN = (ll == 0) ? 1.f/(float)NPFN : 1.f/(float)(BATCH*NPIX);
    k_conv<<<cgrid, 256, 0, stream>>>((ll==0)?bevk:nullptr, srcs[ll],
                                      stin, gg, bb, eps, invN, (ll==0)?1:0,
                                      Bw + (size_t)ll*36864, bptr[ll], dsts[ll],
                                      stc + ll*4096);
  }
  k_head<<<(BATCH*NPIX+255)/256, 256, 0, stream>>>(convA, stc + 4*4096, gptr[4], beptr[4],
                                                   hw, hb, (float*)d_out);
}

// Round 13
// 302.856 us; speedup vs baseline: 1.0737x; 1.0566x over previous
//
#include <hip/hip_runtime.h>

// Round 13: recombine measured winners — single-voxel prefetch-1 p2/p3
// (round-10 form, VGPR ~90, occ ~17%) + p3's BEV scatter (p4 eliminated,
// round 11) + bf16 conv chain (round 12). Dual-voxel reverted (VGPR 152
// halved occupancy).

#define BATCH 2
#define NPTS 100000
#define GNX 176
#define GNY 200
#define GNZ 10
#define NCELL (GNX*GNY*GNZ)
#define PMAX 32
#define MAXV 20000
#define NVOX (BATCH*MAXV)
#define NPFN (NVOX*PMAX)
#define CONVH 200
#define CONVW 176
#define NPIX (CONVH*CONVW)
#define NELEM (BATCH*NPIX*64)
#define SCAN_NB ((NCELL + 1023)/1024)
#define PGRID 1024
#define SHAD 32
#define KNEGINF 0x007FFFFFu   // key(-inf)

typedef __attribute__((ext_vector_type(8))) short short8;
typedef __attribute__((ext_vector_type(4))) float f32x4;

__device__ __forceinline__ unsigned short f2bf(float f){
  unsigned int u = __float_as_uint(f);
  u = (u + 0x7fffu + ((u >> 16) & 1u)) >> 16;
  return (unsigned short)u;
}
__device__ __forceinline__ float bf2f(unsigned short s){
  return __uint_as_float(((unsigned int)s) << 16);
}

__device__ __forceinline__ int voxel_id(float x, float y, float z){
  int ix = (int)floorf(x / 0.4f);
  int iy = (int)floorf((y + 40.0f) / 0.4f);
  int iz = (int)floorf((z + 3.0f) / 0.4f);
  if (ix < 0 || iy < 0 || iz < 0 || ix >= GNX || iy >= GNY || iz >= GNZ) return -1;
  return (ix*GNY + iy)*GNZ + iz;
}

extern "C" __global__ void k_count(const float* __restrict__ pts, int* __restrict__ cellcnt){
  int i = blockIdx.x*256 + threadIdx.x;
  if (i >= BATCH*NPTS) return;
  const float* q = pts + (size_t)i*4;
  int vid = voxel_id(q[0], q[1], q[2]);
  if (vid < 0) return;
  int b = i / NPTS;
  atomicAdd(&cellcnt[b*NCELL + vid], 1);
}

extern "C" __global__ void __launch_bounds__(256) k_blkcount(const int* __restrict__ cellcnt,
                                                             int* __restrict__ blks){
  int b = blockIdx.y, blk = blockIdx.x, t = threadIdx.x;
  int base = blk*1024 + t*4;
  int s = 0;
  #pragma unroll
  for (int i=0;i<4;i++){ int c = base+i; if (c < NCELL) s += (cellcnt[b*NCELL+c] > 0); }
  #pragma unroll
  for (int m=32;m>=1;m>>=1) s += __shfl_xor(s, m);
  __shared__ int red[4];
  if ((t&63)==0) red[t>>6] = s;
  __syncthreads();
  if (t==0) blks[b*512+blk] = red[0]+red[1]+red[2]+red[3];
}

extern "C" __global__ void __launch_bounds__(512) k_scan(int* __restrict__ blks){
  int b = blockIdx.x, t = threadIdx.x;
  __shared__ int l[512];
  int orig = (t < SCAN_NB) ? blks[b*512+t] : 0;
  l[t] = orig;
  __syncthreads();
  for (int o=1;o<512;o<<=1){
    int v = (t>=o) ? l[t-o] : 0;
    __syncthreads();
    l[t] += v;
    __syncthreads();
  }
  if (t < SCAN_NB) blks[b*512+t] = l[t] - orig;   // exclusive
}

extern "C" __global__ void __launch_bounds__(256) k_assign(const int* __restrict__ cellcnt,
    const int* __restrict__ blks, int* __restrict__ slotmap, int* __restrict__ vv,
    int* __restrict__ cnt){
  int b = blockIdx.y, blk = blockIdx.x, t = threadIdx.x;
  int base = blk*1024 + t*4;
  int flag[4]; int s = 0;
  #pragma unroll
  for (int i=0;i<4;i++){
    int c = base+i;
    flag[i] = (c < NCELL) ? (cellcnt[b*NCELL+c] > 0) : 0;
    s += flag[i];
  }
  __shared__ int lds[256];
  lds[t] = s; __syncthreads();
  for (int o=1;o<256;o<<=1){
    int v = (t>=o) ? lds[t-o] : 0;
    __syncthreads();
    lds[t] += v;
    __syncthreads();
  }
  int run = blks[b*512+blk] + (lds[t]-s);
  #pragma unroll
  for (int i=0;i<4;i++){
    int c = base+i;
    if (c >= NCELL) break;
    int sm = -1;
    if (flag[i]){
      if (run < MAXV){
        sm = run;
        vv[b*MAXV+run]  = c;
        cnt[b*MAXV+run] = min(cellcnt[b*NCELL+c], PMAX);
      }
      run++;
    }
    slotmap[b*NCELL+c] = sm;
  }
}

extern "C" __global__ void k_fill(const float* __restrict__ pts, const int* __restrict__ slotmap,
                                  int* __restrict__ fill, int* __restrict__ plist){
  int i = blockIdx.x*256 + threadIdx.x;
  if (i >= BATCH*NPTS) return;
  const float* q = pts + (size_t)i*4;
  int vid = voxel_id(q[0], q[1], q[2]);
  if (vid < 0) return;
  int b = i / NPTS;
  int slot = slotmap[b*NCELL+vid];
  if (slot < 0) return;
  int pos = atomicAdd(&fill[b*MAXV+slot], 1);
  if (pos < PMAX) plist[((size_t)b*MAXV+slot)*PMAX + pos] = i - b*NPTS;
}

// gather sorted points into pvox [NVOX][32] float4 + per-voxel mean [NVOX] float4
extern "C" __global__ void __launch_bounds__(256) k_feat(const float* __restrict__ pts,
    const int* __restrict__ cnt, const int* __restrict__ plist,
    float* __restrict__ pvox, float* __restrict__ mean){
  int g  = threadIdx.x >> 5;
  int fv = blockIdx.x*8 + g;
  int p  = threadIdx.x & 31;
  int b  = fv / MAXV;
  __shared__ int lst[8][32];
  int c = cnt[fv];
  if (p < c) lst[g][p] = plist[(size_t)fv*PMAX + p];
  __syncthreads();
  if (p == 0){
    for (int i=1;i<c;i++){
      int key = lst[g][i]; int j = i-1;
      while (j >= 0 && lst[g][j] > key){ lst[g][j+1] = lst[g][j]; j--; }
      lst[g][j+1] = key;
    }
  }
  __syncthreads();
  float4 pt = make_float4(0.f,0.f,0.f,0.f);
  if (p < c) pt = *(const float4*)(pts + ((size_t)b*NPTS + lst[g][p])*4);
  float sx = pt.x, sy = pt.y, sz = pt.z;
  #pragma unroll
  for (int m=16;m>=1;m>>=1){
    sx += __shfl_xor(sx, m, 32); sy += __shfl_xor(sy, m, 32); sz += __shfl_xor(sz, m, 32);
  }
  float cd = (float)max(c, 1);
  if (p < c) *(float4*)(pvox + ((size_t)fv*32 + p)*4) = pt;
  if (p == 0) *(float4*)(mean + (size_t)fv*4) = make_float4(sx/cd, sy/cd, sz/cd, 0.f);
}

// BEV key init
extern "C" __global__ void k_binit(unsigned* __restrict__ bev){
  int i = blockIdx.x*256 + threadIdx.x;
  if (i*4 >= NELEM) return;
  uint4 v = make_uint4(KNEGINF, KNEGINF, KNEGINF, KNEGINF);
  ((uint4*)bev)[i] = v;
}

#define IN7(pt, mn) {pt.x, pt.y, pt.z, pt.w, pt.x-mn.x, pt.y-mn.y, pt.z-mn.z}

// ============ PFN phases: single-voxel, prefetch-1 ============
extern "C" __global__ void __launch_bounds__(256) k_p1(const float* __restrict__ pvox,
    const float* __restrict__ mean, const int* __restrict__ cnt,
    const float* __restrict__ w1, float* __restrict__ st){
  __shared__ float w1L[224];
  __shared__ float sred[64];
  int tid = threadIdx.x;
  if (tid < 56) ((float4*)w1L)[tid] = ((const float4*)w1)[tid];
  if (tid < 64) sred[tid] = 0.f;
  __syncthreads();
  int w = tid>>6, lane = tid&63, c = lane&31, half = lane>>5;
  const int STR = PGRID*4;
  int fv = blockIdx.x*4 + w;
  int c_n = 0;
  float4 mn_n = make_float4(0.f,0.f,0.f,0.f), pA_n = mn_n;
  if (fv < NVOX){
    c_n  = cnt[fv];
    mn_n = *(const float4*)(mean + (size_t)fv*4);
    pA_n = *(const float4*)(pvox + ((size_t)fv*32 + half)*4);
  }
  float S=0.f, Q=0.f;
  while (fv < NVOX){
    const int fvc = fv;
    const int c_ = c_n;
    const float4 mn = mn_n, pA = pA_n;
    fv += STR;
    if (fv < NVOX){
      c_n  = cnt[fv];
      mn_n = *(const float4*)(mean + (size_t)fv*4);
      pA_n = *(const float4*)(pvox + ((size_t)fv*32 + half)*4);
    }
    {
      float in[7] = IN7(pA, mn);
      float v = 0.f;
      #pragma unroll
      for (int k=0;k<7;k++) v += in[k]*w1L[k*32+c];
      if (half < c_){ S += v; Q += v*v; }
    }
    for (int p = half+2; p < c_; p += 2){
      float4 pt = *(const float4*)(pvox + ((size_t)fvc*32+p)*4);
      float in[7] = IN7(pt, mn);
      float v = 0.f;
      #pragma unroll
      for (int k=0;k<7;k++) v += in[k]*w1L[k*32+c];
      S += v; Q += v*v;
    }
  }
  S += __shfl_xor(S,32); Q += __shfl_xor(Q,32);
  if (half==0){ atomicAdd(&sred[c],S); atomicAdd(&sred[32+c],Q); }
  __syncthreads();
  if (tid<64) atomicAdd(&st[(blockIdx.x&(SHAD-1))*64+tid], sred[tid]);
}

extern "C" __global__ void __launch_bounds__(256) k_p2(const float* __restrict__ pvox,
    const float* __restrict__ mean, const int* __restrict__ cnt,
    const float* __restrict__ w1, const float* __restrict__ g1, const float* __restrict__ b1,
    const float* __restrict__ w2, const float* __restrict__ st1, float* __restrict__ st2,
    float* __restrict__ K2buf){
  __shared__ float w1L[224];
  __shared__ float w2L[2496];
  __shared__ float sred[128];
  int tid = threadIdx.x;
  if (tid < 56) ((float4*)w1L)[tid] = ((const float4*)w1)[tid];
  for (int i=tid;i<624;i+=256) ((float4*)w2L)[i] = ((const float4*)w2)[i];
  if (tid < 128) sred[tid] = 0.f;
  __syncthreads();
  int w = tid>>6, lane = tid&63, c1 = lane&31;
  const float invN = 1.f/(float)NPFN;
  float m1=0.f, v1s=0.f;
  #pragma unroll
  for (int s=0;s<SHAD;s++){ m1 += st1[s*64+c1]; v1s += st1[s*64+32+c1]; }
  m1 *= invN; v1s = v1s*invN - m1*m1;
  float sc1 = g1[c1]*rsqrtf(v1s + 1e-3f);
  float sh1 = b1[c1] - m1*sc1;
  const int STR = PGRID*4;
  int fv = blockIdx.x*4 + w;
  int c_n = 0;
  float4 mn_n = make_float4(0.f,0.f,0.f,0.f), p0_n = mn_n, p1_n = mn_n;
  if (fv < NVOX){
    c_n  = cnt[fv];
    mn_n = *(const float4*)(mean + (size_t)fv*4);
    p0_n = *(const float4*)(pvox + ((size_t)fv*32+0)*4);
    p1_n = *(const float4*)(pvox + ((size_t)fv*32+1)*4);
  }
  float S = 0.f, Q = 0.f;
  while (fv < NVOX){
    const int fvc = fv;
    const int c_ = c_n;
    const float4 mn = mn_n, p0 = p0_n, p1 = p1_n;
    fv += STR;
    if (fv < NVOX){
      c_n  = cnt[fv];
      mn_n = *(const float4*)(mean + (size_t)fv*4);
      p0_n = *(const float4*)(pvox + ((size_t)fv*32+0)*4);
      p1_n = *(const float4*)(pvox + ((size_t)fv*32+1)*4);
    }
    float vm = 0.f, sa = 0.f, sq = 0.f;
    {
      float in[7] = IN7(p0, mn);
      float v1 = 0.f, a2 = 0.f;
      #pragma unroll
      for (int k=0;k<7;k++){ v1 += in[k]*w1L[k*32+c1]; a2 += in[k]*w2L[k*64+lane]; }
      if (c_ > 0){ vm = fmaxf(vm, v1*sc1 + sh1); sa += a2; sq += a2*a2; }
    }
    {
      float in[7] = IN7(p1, mn);
      float v1 = 0.f, a2 = 0.f;
      #pragma unroll
      for (int k=0;k<7;k++){ v1 += in[k]*w1L[k*32+c1]; a2 += in[k]*w2L[k*64+lane]; }
      if (c_ > 1){ vm = fmaxf(vm, v1*sc1 + sh1); sa += a2; sq += a2*a2; }
    }
    for (int p = 2; p < c_; p++){
      float4 pt = *(const float4*)(pvox + ((size_t)fvc*32+p)*4);
      float in[7] = IN7(pt, mn);
      float v1 = 0.f, a2 = 0.f;
      #pragma unroll
      for (int k=0;k<7;k++){ v1 += in[k]*w1L[k*32+c1]; a2 += in[k]*w2L[k*64+lane]; }
      vm = fmaxf(vm, v1*sc1 + sh1);
      sa += a2; sq += a2*a2;
    }
    float k0=0.f,k1=0.f,k2=0.f,k3=0.f;
    #pragma unroll
    for (int j=0;j<32;j+=4){
      k0 += __shfl(vm, j  )*w2L[(7+j )*64+lane];
      k1 += __shfl(vm, j+1)*w2L[(8+j )*64+lane];
      k2 += __shfl(vm, j+2)*w2L[(9+j )*64+lane];
      k3 += __shfl(vm, j+3)*w2L[(10+j)*64+lane];
    }
    float K = (k0+k1)+(k2+k3);
    if (c_) K2buf[(size_t)fvc*64 + lane] = K;
    S += (float)PMAX*K + sa;
    Q += (float)PMAX*K*K + sq + 2.f*K*sa;
  }
  atomicAdd(&sred[lane], S); atomicAdd(&sred[64+lane], Q);
  __syncthreads();
  if (tid < 128) atomicAdd(&st2[(blockIdx.x&(SHAD-1))*128 + tid], sred[tid]);
}

// p3: single-voxel, prefetch-1; scatters raw extreme into BEV (uint key max).
extern "C" __global__ void __launch_bounds__(256) k_p3(const float* __restrict__ pvox,
    const float* __restrict__ mean, const int* __restrict__ cnt, const int* __restrict__ vv,
    const float* __restrict__ w2, const float* __restrict__ g2, const float* __restrict__ b2,
    const float* __restrict__ w3, const float* __restrict__ g3,
    const float* __restrict__ st2, float* __restrict__ st3,
    const float* __restrict__ K2buf, unsigned* __restrict__ bev){
  __shared__ float w2L[2496];
  __shared__ float w3L[4544];
  __shared__ float sred[128];
  int tid = threadIdx.x;
  for (int i=tid;i<624;i+=256)  ((float4*)w2L)[i] = ((const float4*)w2)[i];
  for (int i=tid;i<1136;i+=256) ((float4*)w3L)[i] = ((const float4*)w3)[i];
  if (tid < 128) sred[tid] = 0.f;
  __syncthreads();
  int w = tid>>6, lane = tid&63;
  const float invN = 1.f/(float)NPFN;
  float m2=0.f, v2s=0.f;
  #pragma unroll
  for (int s=0;s<SHAD;s++){ m2 += st2[s*128+lane]; v2s += st2[s*128+64+lane]; }
  m2 *= invN; v2s = v2s*invN - m2*m2;
  float sc2 = g2[lane]*rsqrtf(v2s + 1e-3f);
  float sh2 = b2[lane] - m2*sc2;
  bool pickmax = (g3[lane] >= 0.f);
  const int STR = PGRID*4;
  int fv = blockIdx.x*4 + w;
  int c_n = 0, vv_n = 0; float K2_n = 0.f;
  float4 mn_n = make_float4(0.f,0.f,0.f,0.f), p0_n = mn_n, p1_n = mn_n;
  if (fv < NVOX){
    c_n  = cnt[fv];
    vv_n = vv[fv];
    mn_n = *(const float4*)(mean + (size_t)fv*4);
    K2_n = K2buf[(size_t)fv*64 + lane];
    p0_n = *(const float4*)(pvox + ((size_t)fv*32+0)*4);
    p1_n = *(const float4*)(pvox + ((size_t)fv*32+1)*4);
  }
  float S = 0.f, Q = 0.f;
  while (fv < NVOX){
    const int fvc = fv;
    const int c_ = c_n, vid = vv_n;
    const float K2 = K2_n;
    const float4 mn = mn_n, p0 = p0_n, p1 = p1_n;
    fv += STR;
    if (fv < NVOX){
      c_n  = cnt[fv];
      vv_n = vv[fv];
      mn_n = *(const float4*)(mean + (size_t)fv*4);
      K2_n = K2buf[(size_t)fv*64 + lane];
      p0_n = *(const float4*)(pvox + ((size_t)fv*32+0)*4);
      p1_n = *(const float4*)(pvox + ((size_t)fv*32+1)*4);
    }
    float vm = 0.f, sa = 0.f, sq = 0.f;
    float amx = -3.4e38f, amn = 3.4e38f;
    {
      float in[7] = IN7(p0, mn);
      float a2 = 0.f, a3 = 0.f;
      #pragma unroll
      for (int k=0;k<7;k++){ a2 += in[k]*w2L[k*64+lane]; a3 += in[k]*w3L[k*64+lane]; }
      if (c_ > 0){
        vm = fmaxf(vm, (a2+K2)*sc2 + sh2);
        sa += a3; sq += a3*a3;
        amx = fmaxf(amx, a3); amn = fminf(amn, a3);
      }
    }
    {
      float in[7] = IN7(p1, mn);
      float a2 = 0.f, a3 = 0.f;
      #pragma unroll
      for (int k=0;k<7;k++){ a2 += in[k]*w2L[k*64+lane]; a3 += in[k]*w3L[k*64+lane]; }
      if (c_ > 1){
        vm = fmaxf(vm, (a2+K2)*sc2 + sh2);
        sa += a3; sq += a3*a3;
        amx = fmaxf(amx, a3); amn = fminf(amn, a3);
      }
    }
    for (int p = 2; p < c_; p++){
      float4 pt = *(const float4*)(pvox + ((size_t)fvc*32+p)*4);
      float in[7] = IN7(pt, mn);
      float a2 = 0.f, a3 = 0.f;
      #pragma unroll
      for (int k=0;k<7;k++){ a2 += in[k]*w2L[k*64+lane]; a3 += in[k]*w3L[k*64+lane]; }
      vm = fmaxf(vm, (a2+K2)*sc2 + sh2);
      sa += a3; sq += a3*a3;
      amx = fmaxf(amx, a3); amn = fminf(amn, a3);
    }
    float k0=0.f,k1=0.f,k2=0.f,k3=0.f;
    #pragma unroll
    for (int j=0;j<64;j+=4){
      k0 += __shfl(vm, j  )*w3L[(7+j )*64+lane];
      k1 += __shfl(vm, j+1)*w3L[(8+j )*64+lane];
      k2 += __shfl(vm, j+2)*w3L[(9+j )*64+lane];
      k3 += __shfl(vm, j+3)*w3L[(10+j)*64+lane];
    }
    float K3 = (k0+k1)+(k2+k3);
    if (c_){
      float raw = (pickmax ? amx : amn) + K3;
      if (!pickmax) raw = -raw;
      unsigned u = __float_as_uint(raw);
      unsigned key = (u & 0x80000000u) ? ~u : (u | 0x80000000u);
      int bb = fvc / MAXV;
      int cx = vid / (GNY*GNZ);
      int cy = (vid / GNZ) % GNY;
      atomicMax(bev + (((size_t)bb*NPIX + (size_t)cy*CONVW + cx)*64) + lane, key);
    }
    S += (float)PMAX*K3 + sa;
    Q += (float)PMAX*K3*K3 + sq + 2.f*K3*sa;
  }
  atomicAdd(&sred[lane], S); atomicAdd(&sred[64+lane], Q);
  __syncthreads();
  if (tid < 128) atomicAdd(&st3[(blockIdx.x&(SHAD-1))*128 + tid], sred[tid]);
}

// ---- weight prepack: [oc][ic][3][3] f32 -> [tap][oc][ic] bf16, 5 layers
extern "C" __global__ void k_wprep(const float* __restrict__ cs_w, const float* __restrict__ rpn_w,
                                   unsigned short* __restrict__ Bw){
  int i = blockIdx.x*256 + threadIdx.x;
  if (i >= 5*36864) return;
  int l = i/36864, r = i - l*36864;
  int tap = r >> 12, oc = (r >> 6) & 63, ic = r & 63;
  const float* src = (l < 2) ? (cs_w + (size_t)l*36864) : (rpn_w + (size_t)(l-2)*36864);
  Bw[i] = f2bf(src[((size_t)oc*64 + ic)*9 + tap]);
}

// ---- conv3x3: implicit GEMM, bf16 MFMA, bf16 chain (layer0 reads uint keys)
#define CTH 8
extern "C" __global__ void __launch_bounds__(256) k_conv(const unsigned* __restrict__ inK,
    const unsigned short* __restrict__ inH,
    const float* __restrict__ stin, const float* __restrict__ g, const float* __restrict__ be,
    float eps, float invN, int raw0,
    const unsigned short* __restrict__ Bw, const float* __restrict__ bias,
    unsigned short* __restrict__ out, float* __restrict__ st){
  const int b  = blockIdx.z;
  const int x0 = blockIdx.x*16, y0 = blockIdx.y*CTH;
  const int tid = threadIdx.x;
  const int w = tid >> 6, l = tid & 63;
  const int l15 = l & 15, quad = l >> 4;
  const int bid = (blockIdx.z*gridDim.y + blockIdx.y)*gridDim.x + blockIdx.x;
  const int shad = bid & (SHAD-1);

  __shared__ unsigned short smemA[(CTH+2)*18*64];
  __shared__ float bnsc[64], bnsh[64];
  __shared__ float sA[64], sQ[64];
  if (tid < 64){
    sA[tid] = 0.f; sQ[tid] = 0.f;
    float m = 0.f, q = 0.f;
    #pragma unroll
    for (int s=0;s<SHAD;s++){ m += stin[s*128+tid]; q += stin[s*128+64+tid]; }
    m *= invN;
    float va = q*invN - m*m;
    float sc = g[tid]*rsqrtf(va + eps);
    bnsc[tid] = sc; bnsh[tid] = be[tid] - m*sc;
  }
  __syncthreads();

  for (int i = tid; i < (CTH+2)*18*8; i += 256){
    int pos = i >> 3, jb = i & 7;
    int yp = pos/18, xp = pos - yp*18;
    int gy = y0 + yp - 1, gx = x0 + xp - 1;
    unsigned short h[8] = {0,0,0,0,0,0,0,0};
    if (gy >= 0 && gy < CONVH && gx >= 0 && gx < CONVW){
      size_t ebase = ((size_t)b*NPIX + (size_t)gy*CONVW + gx)*64 + jb*8;
      float f[8];
      if (raw0){
        uint4 u0 = *(const uint4*)(inK + ebase);
        uint4 u1 = *(const uint4*)(inK + ebase + 4);
        unsigned kk[8] = {u0.x,u0.y,u0.z,u0.w,u1.x,u1.y,u1.z,u1.w};
        #pragma unroll
        for (int k=0;k<8;k++){
          unsigned key = kk[k];
          unsigned u = (key & 0x80000000u) ? (key & 0x7fffffffu) : ~key;
          float v = __uint_as_float(u);
          int c = jb*8 + k;
          if (bnsc[c] < 0.f) v = -v;
          f[k] = v;
        }
      } else {
        uint4 v4 = *(const uint4*)(inH + ebase);
        unsigned uu[4] = {v4.x, v4.y, v4.z, v4.w};
        #pragma unroll
        for (int e=0;e<4;e++){
          f[e*2]   = bf2f((unsigned short)(uu[e] & 0xffffu));
          f[e*2+1] = bf2f((unsigned short)(uu[e] >> 16));
        }
      }
      #pragma unroll
      for (int k=0;k<8;k++){
        int c = jb*8 + k;
        h[k] = f2bf(fmaxf(f[k]*bnsc[c] + bnsh[c], 0.f));
      }
    }
    int jsw = jb ^ (xp & 7);
    *(uint4*)&smemA[pos*64 + jsw*8] = *(uint4*)h;
  }
  __syncthreads();

  f32x4 acc[2][4] = {{{0.f,0.f,0.f,0.f},{0.f,0.f,0.f,0.f},{0.f,0.f,0.f,0.f},{0.f,0.f,0.f,0.f}},
                     {{0.f,0.f,0.f,0.f},{0.f,0.f,0.f,0.f},{0.f,0.f,0.f,0.f},{0.f,0.f,0.f,0.f}}};
  #pragma unroll
  for (int tap = 0; tap < 9; tap++){
    const int dy = tap/3, dx = tap - dy*3;
    const int xp = l15 + dx;
    const int xm = xp & 7;
    short8 b0[4], b1[4];
    #pragma unroll
    for (int nt = 0; nt < 4; nt++){
      const unsigned short* bp = Bw + (((size_t)tap*64 + nt*16 + l15)*64 + quad*8);
      b0[nt] = *(const short8*)bp;
      b1[nt] = *(const short8*)(bp + 32);
    }
    #pragma unroll
    for (int rr = 0; rr < 2; rr++){
      int yp = 2*w + rr + dy;
      int abase = (yp*18 + xp)*64;
      short8 aL = *(const short8*)&smemA[abase + ((quad    ) ^ xm)*8];
      short8 aH = *(const short8*)&smemA[abase + ((4 + quad) ^ xm)*8];
      #pragma unroll
      for (int nt = 0; nt < 4; nt++)
        acc[rr][nt] = __builtin_amdgcn_mfma_f32_16x16x32_bf16(aL, b0[nt], acc[rr][nt], 0,0,0);
      #pragma unroll
      for (int nt = 0; nt < 4; nt++)
        acc[rr][nt] = __builtin_amdgcn_mfma_f32_16x16x32_bf16(aH, b1[nt], acc[rr][nt], 0,0,0);
    }
  }

  #pragma unroll
  for (int nt = 0; nt < 4; nt++){
    int oc = nt*16 + l15;
    float bv = bias[oc];
    float s = 0.f, q = 0.f;
    #pragma unroll
    for (int rr = 0; rr < 2; rr++){
      int y = y0 + 2*w + rr;
      size_t rbase = ((size_t)b*NPIX + (size_t)y*CONVW)*64;
      #pragma unroll
      for (int r = 0; r < 4; r++){
        float v = acc[rr][nt][r] + bv;
        int x = x0 + quad*4 + r;
        out[rbase + (size_t)x*64 + oc] = f2bf(v);
        s += v; q += v*v;
      }
    }
    s += __shfl_xor(s, 16); s += __shfl_xor(s, 32);
    q += __shfl_xor(q, 16); q += __shfl_xor(q, 32);
    if (quad == 0){ atomicAdd(&sA[oc], s); atomicAdd(&sQ[oc], q); }
  }
  __syncthreads();
  if (tid < 64){
    atomicAdd(&st[shad*128 + tid], sA[tid]);
    atomicAdd(&st[shad*128 + 64 + tid], sQ[tid]);
  }
}

// ---- head 1x1: bf16 in + fused BN/relu of last conv layer
extern "C" __global__ void __launch_bounds__(256) k_head(const unsigned short* __restrict__ in,
    const float* __restrict__ stin, const float* __restrict__ g, const float* __restrict__ be,
    const float* __restrict__ hw, const float* __restrict__ hb, float* __restrict__ outp){
  __shared__ float bnsc[64], bnsh[64];
  int tid = threadIdx.x;
  if (tid < 64){
    const float invN = 1.f/(float)(BATCH*NPIX);
    float m = 0.f, q = 0.f;
    #pragma unroll
    for (int s=0;s<SHAD;s++){ m += stin[s*128+tid]; q += stin[s*128+64+tid]; }
    m *= invN;
    float va = q*invN - m*m;
    float sc = g[tid]*rsqrtf(va + 1e-5f);
    bnsc[tid] = sc; bnsh[tid] = be[tid] - m*sc;
  }
  __syncthreads();
  int i = blockIdx.x*256 + tid;
  if (i >= BATCH*NPIX) return;
  const uint4* p = (const uint4*)(in + (size_t)i*64);
  float a0 = hb[0], a1 = hb[1], a2 = hb[2];
  #pragma unroll
  for (int jb = 0; jb < 8; jb++){
    uint4 u = p[jb];
    unsigned uu[4] = {u.x, u.y, u.z, u.w};
    #pragma unroll
    for (int e = 0; e < 4; e++){
      int ic = jb*8 + e*2;
      float v0 = bf2f((unsigned short)(uu[e] & 0xffffu));
      float v1 = bf2f((unsigned short)(uu[e] >> 16));
      float h0 = fmaxf(v0*bnsc[ic]   + bnsh[ic],   0.f);
      float h1 = fmaxf(v1*bnsc[ic+1] + bnsh[ic+1], 0.f);
      a0 += h0*hw[ic] + h1*hw[ic+1];
      a1 += h0*hw[64+ic] + h1*hw[64+ic+1];
      a2 += h0*hw[128+ic] + h1*hw[128+ic+1];
    }
  }
  size_t o = (size_t)i*3;
  outp[o+0] = a0; outp[o+1] = a1; outp[o+2] = a2;
}

extern "C" void kernel_launch(void* const* d_in, const int* in_sizes, int n_in,
                              void* d_out, int out_size, void* d_ws, size_t ws_size,
                              hipStream_t stream){
  (void)in_sizes; (void)n_in; (void)out_size;
  const float* pts   = (const float*)d_in[0];
  const float* w1    = (const float*)d_in[1];
  const float* g1    = (const float*)d_in[2];
  const float* b1    = (const float*)d_in[3];
  const float* w2    = (const float*)d_in[4];
  const float* g2    = (const float*)d_in[5];
  const float* b2    = (const float*)d_in[6];
  const float* w3    = (const float*)d_in[7];
  const float* g3    = (const float*)d_in[8];
  const float* b3    = (const float*)d_in[9];
  const float* cs_w  = (const float*)d_in[10];
  const float* cs_b  = (const float*)d_in[11];
  const float* cs_g  = (const float*)d_in[12];
  const float* cs_be = (const float*)d_in[13];
  const float* rpn_w = (const float*)d_in[14];
  const float* rpn_b = (const float*)d_in[15];
  const float* rpn_g = (const float*)d_in[16];
  const float* rpn_be= (const float*)d_in[17];
  const float* hw    = (const float*)d_in[18];
  const float* hb    = (const float*)d_in[19];

  char* ws = (char*)d_ws;
  size_t off = 0;
  auto alloc = [&](size_t bytes)->char*{
    char* p = ws + off; off += (bytes + 255) & ~(size_t)255; return p;
  };
  // ---- zero region (single memset) ----
  int*   cellcnt = (int*)  alloc((size_t)BATCH*NCELL*4);
  int*   vv      = (int*)  alloc((size_t)NVOX*4);
  int*   cnt     = (int*)  alloc((size_t)NVOX*4);
  int*   fill    = (int*)  alloc((size_t)NVOX*4);
  float* stats   = (float*)alloc(131072);
  size_t zbytes  = off;
  // ---- no-init region ----
  int*   slotmap = (int*)  alloc((size_t)BATCH*NCELL*4);
  int*   blks    = (int*)  alloc((size_t)BATCH*512*4);
  int*   plist   = (int*)  alloc((size_t)NVOX*PMAX*4);      // conv alias start, 5.12MB
  float* pvox    = (float*)alloc((size_t)NVOX*PMAX*16);     // 20.48MB
  float* mean    = (float*)alloc((size_t)NVOX*16);          // 0.64MB
  float* K2buf   = (float*)alloc((size_t)NVOX*64*4);        // 10.24MB
  unsigned* bevk = (unsigned*)alloc((size_t)NELEM*4);       // 18.02MB (uint keys)
  unsigned short* Bw = (unsigned short*)alloc((size_t)5*36864*2);
  if (off > ws_size) return;

  float* st1 = stats;            // [32][64]
  float* st2 = stats + 2048;     // [32][128]
  float* st3 = stats + 6144;     // [32][128]
  float* stc = stats + 10240;    // 5 x [32][128]

  // conv ping-pong (bf16, 9.01MB each) aliases plist..pvox (dead before convs)
  unsigned short* convA = (unsigned short*)plist;
  unsigned short* convB = (unsigned short*)((char*)plist + 9011200);

  hipMemsetAsync(ws, 0, zbytes, stream);

  k_count <<<(BATCH*NPTS+255)/256, 256, 0, stream>>>(pts, cellcnt);
  k_blkcount<<<dim3(SCAN_NB,BATCH), 256, 0, stream>>>(cellcnt, blks);
  k_scan  <<<BATCH, 512, 0, stream>>>(blks);
  k_assign<<<dim3(SCAN_NB,BATCH), 256, 0, stream>>>(cellcnt, blks, slotmap, vv, cnt);
  k_fill  <<<(BATCH*NPTS+255)/256, 256, 0, stream>>>(pts, slotmap, fill, plist);
  k_binit <<<(NELEM/4+255)/256, 256, 0, stream>>>(bevk);
  k_feat  <<<NVOX/8, 256, 0, stream>>>(pts, cnt, plist, pvox, mean);

  k_p1<<<PGRID, 256, 0, stream>>>(pvox, mean, cnt, w1, st1);
  k_p2<<<PGRID, 256, 0, stream>>>(pvox, mean, cnt, w1, g1, b1, w2, st1, st2, K2buf);
  k_wprep<<<(5*36864+255)/256, 256, 0, stream>>>(cs_w, rpn_w, Bw);
  k_p3<<<PGRID, 256, 0, stream>>>(pvox, mean, cnt, vv, w2, g2, b2, w3, g3, st2, st3,
                                  K2buf, bevk);

  const float* bptr[5]  = {cs_b, cs_b+64,   rpn_b, rpn_b+64,   rpn_b+128};
  const float* gptr[5]  = {cs_g, cs_g+64,   rpn_g, rpn_g+64,   rpn_g+128};
  const float* beptr[5] = {cs_be,cs_be+64,  rpn_be,rpn_be+64,  rpn_be+128};
  const unsigned short* srcs[5] = {nullptr, convA, convB, convA, convB};
  unsigned short*       dsts[5] = {convA, convB, convA, convB, convA};
  dim3 cgrid(CONVW/16, CONVH/CTH, BATCH);
  for (int ll = 0; ll < 5; ll++){
    const float* stin = (ll == 0) ? st3 : (stc + (ll-1)*4096);
    const float* gg   = (ll == 0) ? g3 : gptr[ll-1];
    const float* bb   = (ll == 0) ? b3 : beptr[ll-1];
    float eps  = (ll == 0) ? 1e-3f : 1e-5f;
    float invN = (ll == 0) ? 1.f/(float)NPFN : 1.f/(float)(BATCH*NPIX);
    k_conv<<<cgrid, 256, 0, stream>>>((ll==0)?bevk:nullptr, srcs[ll],
                                      stin, gg, bb, eps, invN, (ll==0)?1:0,
                                      Bw + (size_t)ll*36864, bptr[ll], dsts[ll],
                                      stc + ll*4096);
  }
  k_head<<<(BATCH*NPIX+255)/256, 256, 0, stream>>>(convA, stc + 4*4096, gptr[4], beptr[4],
                                                   hw, hb, (float*)d_out);
}